// Round 1
// baseline (2429.530 us; speedup 1.0000x reference)
//
#include <hip/hip_runtime.h>
#include <hip/hip_bf16.h>
#include <math.h>

#define D_IN 128
#define D_HID 128
#define D_OUT 64
#define BN_EPS 1e-5f
#define SLOPE 0.01f
#define NSCALE 1.8f

__device__ inline void atomAddF(float* p, float v) {
#if defined(__gfx90a__) || defined(__gfx942__) || defined(__gfx950__)
    unsafeAtomicAdd(p, v);
#else
    atomicAdd(p, v);
#endif
}

__global__ void k_deg(const int* __restrict__ dst, int* __restrict__ deg, int E) {
    int e = blockIdx.x * blockDim.x + threadIdx.x;
    if (e < E) atomicAdd(&deg[dst[e]], 1);
}

__global__ void k_dinv(const int* __restrict__ deg, float* __restrict__ dinv, int n) {
    int i = blockIdx.x * blockDim.x + threadIdx.x;
    if (i < n) dinv[i] = rsqrtf((float)deg[i] + 1.0f);
}

// h = x @ W1 + b1 ; W1 (128x128, 64KB) staged in LDS, 2 rows in flight, 64 rows/block
__global__ __launch_bounds__(256) void k_gemm1(const float* __restrict__ x,
        const float* __restrict__ W1, const float* __restrict__ b1,
        float* __restrict__ h, int n) {
    __shared__ float w1s[D_IN * D_HID];
    __shared__ float xs[2][D_IN];
    for (int i = threadIdx.x; i < D_IN * D_HID; i += 256) w1s[i] = W1[i];
    int sub = threadIdx.x >> 7, col = threadIdx.x & 127;
    float bb = b1[col];
    int row0 = blockIdx.x * 64;
    for (int rp = 0; rp < 64; rp += 2) {
        __syncthreads();
        int rr = row0 + rp + sub;
        xs[sub][col] = (rr < n) ? x[(size_t)rr * D_IN + col] : 0.f;
        __syncthreads();
        float acc = bb;
#pragma unroll 16
        for (int k = 0; k < D_IN; ++k) acc = fmaf(xs[sub][k], w1s[k * D_HID + col], acc);
        if (rr < n) h[(size_t)rr * D_HID + col] = acc;
    }
}

// agg[dst] += h[src] * dinv[src]*dinv[dst]; one wave per edge, float2 per lane
__global__ __launch_bounds__(256) void k_spmm1(const int* __restrict__ src,
        const int* __restrict__ dst, const float* __restrict__ dinv,
        const float* __restrict__ h, float* __restrict__ agg, int E) {
    int e = (blockIdx.x << 2) + (threadIdx.x >> 6);
    if (e >= E) return;
    int lane = threadIdx.x & 63;
    int s = src[e], d = dst[e];
    float w = dinv[s] * dinv[d];
    float2 v = ((const float2*)(h + (size_t)s * D_HID))[lane];
    float* ad = agg + (size_t)d * D_HID + 2 * lane;
    atomAddF(ad, v.x * w);
    atomAddF(ad + 1, v.y * w);
}

// agg += h * dinv^2 (self loop), accumulate per-column sum / sumsq
__global__ __launch_bounds__(128) void k_selfbn(const float* __restrict__ h,
        float* __restrict__ agg, const float* __restrict__ dinv,
        float* __restrict__ accum, int n) {
    int col = threadIdx.x;
    float sum = 0.f, sumsq = 0.f;
    for (int r = blockIdx.x; r < n; r += gridDim.x) {
        float di = dinv[r];
        float sl = di * di;
        size_t idx = (size_t)r * D_HID + col;
        float v = agg[idx] + h[idx] * sl;
        agg[idx] = v;
        sum += v;
        sumsq += v * v;
    }
    atomAddF(&accum[col], sum);
    atomAddF(&accum[D_HID + col], sumsq);
}

__global__ void k_bnfinal(float* __restrict__ accum, const float* __restrict__ gamma,
        const float* __restrict__ beta, float inv_n) {
    int c = threadIdx.x;
    float mean = accum[c] * inv_n;
    float var = accum[D_HID + c] * inv_n - mean * mean;
    float sc = gamma[c] * rsqrtf(var + BN_EPS);
    accum[c] = sc;
    accum[D_HID + c] = beta[c] - mean * sc;
}

// l = lrelu(bn(hf)) @ Wmu + bmu ; per-row L2 norm scale s = 1.8/max(||l||,1e-12)
// one wave per row (64 lanes = 64 cols); Wmu (32KB) in LDS; 64 rows per block
__global__ __launch_bounds__(256) void k_gemm2(const float* __restrict__ hf,
        const float* __restrict__ Wmu, const float* __restrict__ bmu,
        const float* __restrict__ accum, float* __restrict__ l,
        float* __restrict__ sOut, int n) {
    __shared__ float wms[D_HID * D_OUT];
    __shared__ float scs[D_HID], shs[D_HID];
    __shared__ float xs[4][D_HID];
    for (int i = threadIdx.x; i < D_HID * D_OUT; i += 256) wms[i] = Wmu[i];
    for (int i = threadIdx.x; i < D_HID; i += 256) {
        scs[i] = accum[i];
        shs[i] = accum[D_HID + i];
    }
    __syncthreads();
    int wid = threadIdx.x >> 6, lane = threadIdx.x & 63;
    float bb = bmu[lane];
    int row0 = blockIdx.x * 64 + wid * 16;
    for (int rp = 0; rp < 16; ++rp) {
        int r = row0 + rp;
        if (r >= n) break;  // r is wave-uniform
        size_t base = (size_t)r * D_HID;
        float v0 = hf[base + lane] * scs[lane] + shs[lane];
        float v1 = hf[base + 64 + lane] * scs[64 + lane] + shs[64 + lane];
        v0 = v0 > 0.f ? v0 : SLOPE * v0;
        v1 = v1 > 0.f ? v1 : SLOPE * v1;
        xs[wid][lane] = v0;
        xs[wid][64 + lane] = v1;
        float acc = bb;
#pragma unroll 16
        for (int k = 0; k < D_HID; ++k) acc = fmaf(xs[wid][k], wms[k * D_OUT + lane], acc);
        float ss = acc * acc;
        for (int off = 32; off >= 1; off >>= 1) ss += __shfl_xor(ss, off, 64);
        float sv = NSCALE / fmaxf(sqrtf(ss), 1e-12f);
        l[(size_t)r * D_OUT + lane] = acc;
        if (lane == 0) sOut[r] = sv;
    }
}

// mu[dst] += l[src]*w ; lsd[dst] += l[src]*s[src]*w ; one wave per edge
__global__ __launch_bounds__(256) void k_spmm2(const int* __restrict__ src,
        const int* __restrict__ dst, const float* __restrict__ dinv,
        const float* __restrict__ l, const float* __restrict__ s,
        float* __restrict__ mu, float* __restrict__ lsd, int E) {
    int e = (blockIdx.x << 2) + (threadIdx.x >> 6);
    if (e >= E) return;
    int lane = threadIdx.x & 63;
    int a = src[e], d = dst[e];
    float w = dinv[a] * dinv[d];
    float lv = l[(size_t)a * D_OUT + lane];
    float sv = s[a];
    atomAddF(&mu[(size_t)d * D_OUT + lane], lv * w);
    atomAddF(&lsd[(size_t)d * D_OUT + lane], lv * sv * w);
}

// add self-loop terms, zeta = mu + noise*exp(logstd)
__global__ void k_final(const float* __restrict__ l, const float* __restrict__ s,
        const float* __restrict__ dinv, const float* __restrict__ noise,
        float* __restrict__ mu, float* __restrict__ lsd, float* __restrict__ zeta,
        int n) {
    int i = blockIdx.x * blockDim.x + threadIdx.x;
    if (i >= n * D_OUT) return;
    int r = i >> 6;
    float di = dinv[r];
    float sl = di * di;
    float lv = l[i];
    float m = mu[i] + lv * sl;
    float ls = lsd[i] + lv * s[r] * sl;
    mu[i] = m;
    lsd[i] = ls;
    zeta[i] = m + noise[i] * expf(ls);
}

extern "C" void kernel_launch(void* const* d_in, const int* in_sizes, int n_in,
                              void* d_out, int out_size, void* d_ws, size_t ws_size,
                              hipStream_t stream) {
    const float* x     = (const float*)d_in[0];
    const int*   esrc  = (const int*)d_in[1];
    const int*   edst  = (const int*)d_in[2];
    const float* W1    = (const float*)d_in[3];
    const float* b1    = (const float*)d_in[4];
    const float* gamma = (const float*)d_in[5];
    const float* beta  = (const float*)d_in[6];
    const float* Wmu   = (const float*)d_in[7];
    const float* bmu   = (const float*)d_in[8];
    const float* noise = (const float*)d_in[9];
    int N = in_sizes[0] / D_IN;
    int E = in_sizes[1];

    float* out  = (float*)d_out;
    float* mu   = out;
    float* lsd  = out + (size_t)N * D_OUT;
    float* zeta = out + 2 * (size_t)N * D_OUT;

    char* ws = (char*)d_ws;
    size_t off = 0;
    int* deg     = (int*)(ws + off);   off += (size_t)N * 4;
    float* accum = (float*)(ws + off); off += 1024;
    float* agg   = (float*)(ws + off); off += (size_t)N * D_HID * 4;
    size_t zbytes = off;               // deg + accum + agg need zeroing
    float* dinv  = (float*)(ws + off); off += (size_t)N * 4;
    float* h     = (float*)(ws + off); off += (size_t)N * D_HID * 4;
    float* l     = (float*)(ws + off); off += (size_t)N * D_OUT * 4;
    float* s     = (float*)(ws + off); off += (size_t)N * 4;

    hipMemsetAsync(d_ws, 0, zbytes, stream);
    hipMemsetAsync(d_out, 0, 2 * (size_t)N * D_OUT * sizeof(float), stream);

    k_deg<<<(E + 255) / 256, 256, 0, stream>>>(edst, deg, E);
    k_dinv<<<(N + 255) / 256, 256, 0, stream>>>(deg, dinv, N);
    k_gemm1<<<(N + 63) / 64, 256, 0, stream>>>(x, W1, b1, h, N);
    k_spmm1<<<(E + 3) / 4, 256, 0, stream>>>(esrc, edst, dinv, h, agg, E);
    k_selfbn<<<1024, 128, 0, stream>>>(h, agg, dinv, accum, N);
    k_bnfinal<<<1, 128, 0, stream>>>(accum, gamma, beta, 1.0f / (float)N);
    k_gemm2<<<(N + 63) / 64, 256, 0, stream>>>(agg, Wmu, bmu, accum, l, s, N);
    k_spmm2<<<(E + 3) / 4, 256, 0, stream>>>(esrc, edst, dinv, l, s, mu, lsd, E);
    k_final<<<((size_t)N * D_OUT + 255) / 256, 256, 0, stream>>>(l, s, dinv, noise, mu, lsd, zeta, N);
}

// Round 2
// 915.784 us; speedup vs baseline: 2.6530x; 2.6530x over previous
//
#include <hip/hip_runtime.h>
#include <hip/hip_bf16.h>
#include <math.h>

#define D_IN 128
#define D_HID 128
#define D_OUT 64
#define BN_EPS 1e-5f
#define SLOPE 0.01f
#define NSCALE 1.8f

__device__ inline void atomAddF(float* p, float v) {
#if defined(__gfx90a__) || defined(__gfx942__) || defined(__gfx950__)
    unsafeAtomicAdd(p, v);
#else
    atomicAdd(p, v);
#endif
}

__global__ void k_deg(const int* __restrict__ dst, int* __restrict__ deg, int E) {
    int e = blockIdx.x * blockDim.x + threadIdx.x;
    if (e < E) atomicAdd(&deg[dst[e]], 1);
}

__global__ void k_dinv(const int* __restrict__ deg, float* __restrict__ dinv, int n) {
    int i = blockIdx.x * blockDim.x + threadIdx.x;
    if (i < n) dinv[i] = rsqrtf((float)deg[i] + 1.0f);
}

// --- scan: rowptr = exclusive_prefix(deg) -------------------------------
__global__ void k_scanA(const int* __restrict__ deg, int* __restrict__ bsum, int n) {
    __shared__ int sh[256];
    int i = blockIdx.x * 256 + threadIdx.x;
    sh[threadIdx.x] = (i < n) ? deg[i] : 0;
    __syncthreads();
    for (int off = 128; off >= 1; off >>= 1) {
        if (threadIdx.x < off) sh[threadIdx.x] += sh[threadIdx.x + off];
        __syncthreads();
    }
    if (threadIdx.x == 0) bsum[blockIdx.x] = sh[0];
}

__global__ void k_scanB(int* __restrict__ bsum, int nb) {  // single block, nb <= 512
    __shared__ int sh[512];
    int v = (threadIdx.x < nb) ? bsum[threadIdx.x] : 0;
    sh[threadIdx.x] = v;
    __syncthreads();
    for (int off = 1; off < 512; off <<= 1) {
        int t = (threadIdx.x >= off) ? sh[threadIdx.x - off] : 0;
        __syncthreads();
        sh[threadIdx.x] += t;
        __syncthreads();
    }
    if (threadIdx.x < nb) bsum[threadIdx.x] = sh[threadIdx.x] - v;  // exclusive
}

__global__ void k_scanC(const int* __restrict__ deg, const int* __restrict__ bsum,
                        int* __restrict__ rowptr, int n) {
    __shared__ int sh[256];
    int i = blockIdx.x * 256 + threadIdx.x;
    int v = (i < n) ? deg[i] : 0;
    sh[threadIdx.x] = v;
    __syncthreads();
    for (int off = 1; off < 256; off <<= 1) {
        int t = (threadIdx.x >= off) ? sh[threadIdx.x - off] : 0;
        __syncthreads();
        sh[threadIdx.x] += t;
        __syncthreads();
    }
    int excl = sh[threadIdx.x] - v + bsum[blockIdx.x];
    if (i < n) rowptr[i] = excl;
    if (i == n - 1) rowptr[n] = excl + v;
}

// scatter edges into CSR (by dst): col = src, wgt = dinv[src]*dinv[dst]
__global__ void k_scatter(const int* __restrict__ src, const int* __restrict__ dst,
                          const int* __restrict__ rowptr, int* __restrict__ cursor,
                          const float* __restrict__ dinv, int* __restrict__ col,
                          float* __restrict__ wgt, int E) {
    int e = blockIdx.x * blockDim.x + threadIdx.x;
    if (e >= E) return;
    int d = dst[e], s = src[e];
    int p = rowptr[d] + atomicAdd(&cursor[d], 1);
    col[p] = s;
    wgt[p] = dinv[s] * dinv[d];
}

// h = x @ W1 + b1 ; W1 (64KB) staged in LDS
__global__ __launch_bounds__(256) void k_gemm1(const float* __restrict__ x,
        const float* __restrict__ W1, const float* __restrict__ b1,
        float* __restrict__ h, int n) {
    __shared__ float w1s[D_IN * D_HID];
    __shared__ float xs[2][D_IN];
    for (int i = threadIdx.x; i < D_IN * D_HID; i += 256) w1s[i] = W1[i];
    int sub = threadIdx.x >> 7, col = threadIdx.x & 127;
    float bb = b1[col];
    int row0 = blockIdx.x * 64;
    for (int rp = 0; rp < 64; rp += 2) {
        __syncthreads();
        int rr = row0 + rp + sub;
        xs[sub][col] = (rr < n) ? x[(size_t)rr * D_IN + col] : 0.f;
        __syncthreads();
        float acc = bb;
#pragma unroll 16
        for (int k = 0; k < D_IN; ++k) acc = fmaf(xs[sub][k], w1s[k * D_HID + col], acc);
        if (rr < n) h[(size_t)rr * D_HID + col] = acc;
    }
}

// pull-mode SpMM1: agg[d] = sum_in h[src]*w + h[d]*dinv[d]^2 ; one wave per node
__global__ __launch_bounds__(256) void k_spmm1_csr(const int* __restrict__ rowptr,
        const int* __restrict__ col, const float* __restrict__ wgt,
        const float* __restrict__ h, const float* __restrict__ dinv,
        float* __restrict__ agg, int n) {
    int node = (blockIdx.x << 2) + (threadIdx.x >> 6);
    if (node >= n) return;
    int lane = threadIdx.x & 63;
    int beg = rowptr[node], end = rowptr[node + 1];
    float di = dinv[node];
    float slw = di * di;
    float2 acc = ((const float2*)(h + (size_t)node * D_HID))[lane];
    acc.x *= slw; acc.y *= slw;
    for (int p = beg; p < end; ++p) {
        int c = col[p];
        float w = wgt[p];
        float2 v = ((const float2*)(h + (size_t)c * D_HID))[lane];
        acc.x = fmaf(v.x, w, acc.x);
        acc.y = fmaf(v.y, w, acc.y);
    }
    ((float2*)(agg + (size_t)node * D_HID))[lane] = acc;
}

// per-column sum / sumsq of agg
__global__ __launch_bounds__(128) void k_bnstats(const float* __restrict__ agg,
        float* __restrict__ accum, int n) {
    int col = threadIdx.x;
    float sum = 0.f, sq = 0.f;
    for (int r = blockIdx.x; r < n; r += gridDim.x) {
        float v = agg[(size_t)r * D_HID + col];
        sum += v;
        sq += v * v;
    }
    atomAddF(&accum[col], sum);
    atomAddF(&accum[D_HID + col], sq);
}

__global__ void k_bnfinal(float* __restrict__ accum, const float* __restrict__ gamma,
        const float* __restrict__ beta, float inv_n) {
    int c = threadIdx.x;
    float mean = accum[c] * inv_n;
    float var = accum[D_HID + c] * inv_n - mean * mean;
    float sc = gamma[c] * rsqrtf(var + BN_EPS);
    accum[c] = sc;
    accum[D_HID + c] = beta[c] - mean * sc;
}

// l = lrelu(bn(agg)) @ Wmu + bmu ; s = 1.8/max(||l||,1e-12)
__global__ __launch_bounds__(256) void k_gemm2(const float* __restrict__ hf,
        const float* __restrict__ Wmu, const float* __restrict__ bmu,
        const float* __restrict__ accum, float* __restrict__ l,
        float* __restrict__ sOut, int n) {
    __shared__ float wms[D_HID * D_OUT];
    __shared__ float scs[D_HID], shs[D_HID];
    __shared__ float xs[4][D_HID];
    for (int i = threadIdx.x; i < D_HID * D_OUT; i += 256) wms[i] = Wmu[i];
    for (int i = threadIdx.x; i < D_HID; i += 256) {
        scs[i] = accum[i];
        shs[i] = accum[D_HID + i];
    }
    __syncthreads();
    int wid = threadIdx.x >> 6, lane = threadIdx.x & 63;
    float bb = bmu[lane];
    int row0 = blockIdx.x * 64 + wid * 16;
    for (int rp = 0; rp < 16; ++rp) {
        int r = row0 + rp;
        if (r >= n) break;  // wave-uniform
        size_t base = (size_t)r * D_HID;
        float v0 = hf[base + lane] * scs[lane] + shs[lane];
        float v1 = hf[base + 64 + lane] * scs[64 + lane] + shs[64 + lane];
        v0 = v0 > 0.f ? v0 : SLOPE * v0;
        v1 = v1 > 0.f ? v1 : SLOPE * v1;
        xs[wid][lane] = v0;
        xs[wid][64 + lane] = v1;
        float acc = bb;
#pragma unroll 16
        for (int k = 0; k < D_HID; ++k) acc = fmaf(xs[wid][k], wms[k * D_OUT + lane], acc);
        float ss = acc * acc;
        for (int off = 32; off >= 1; off >>= 1) ss += __shfl_xor(ss, off, 64);
        float sv = NSCALE / fmaxf(sqrtf(ss), 1e-12f);
        l[(size_t)r * D_OUT + lane] = acc;
        if (lane == 0) sOut[r] = sv;
    }
}

// pull-mode SpMM2 + self-loop + reparam, one wave per node (64 lanes = 64 cols)
__global__ __launch_bounds__(256) void k_spmm2_csr(const int* __restrict__ rowptr,
        const int* __restrict__ col, const float* __restrict__ wgt,
        const float* __restrict__ l, const float* __restrict__ s,
        const float* __restrict__ dinv, const float* __restrict__ noise,
        float* __restrict__ mu, float* __restrict__ lsd, float* __restrict__ zeta,
        int n) {
    int node = (blockIdx.x << 2) + (threadIdx.x >> 6);
    if (node >= n) return;
    int lane = threadIdx.x & 63;
    int beg = rowptr[node], end = rowptr[node + 1];
    float di = dinv[node];
    float slw = di * di;
    float lv = l[(size_t)node * D_OUT + lane];
    float accm = lv * slw;
    float accl = lv * s[node] * slw;
    for (int p = beg; p < end; ++p) {
        int c = col[p];
        float w = wgt[p];
        float v = l[(size_t)c * D_OUT + lane];
        accm = fmaf(v, w, accm);
        accl = fmaf(v * s[c], w, accl);
    }
    size_t idx = (size_t)node * D_OUT + lane;
    float m = accm;
    mu[idx] = m;
    lsd[idx] = accl;
    zeta[idx] = m + noise[idx] * expf(accl);
}

extern "C" void kernel_launch(void* const* d_in, const int* in_sizes, int n_in,
                              void* d_out, int out_size, void* d_ws, size_t ws_size,
                              hipStream_t stream) {
    const float* x     = (const float*)d_in[0];
    const int*   esrc  = (const int*)d_in[1];
    const int*   edst  = (const int*)d_in[2];
    const float* W1    = (const float*)d_in[3];
    const float* b1    = (const float*)d_in[4];
    const float* gamma = (const float*)d_in[5];
    const float* beta  = (const float*)d_in[6];
    const float* Wmu   = (const float*)d_in[7];
    const float* bmu   = (const float*)d_in[8];
    const float* noise = (const float*)d_in[9];
    int N = in_sizes[0] / D_IN;
    int E = in_sizes[1];
    int nb = (N + 255) / 256;

    float* out  = (float*)d_out;
    float* mu   = out;
    float* lsd  = out + (size_t)N * D_OUT;
    float* zeta = out + 2 * (size_t)N * D_OUT;

    char* ws = (char*)d_ws;
    size_t off = 0;
    // zeroed region first: deg, cursor, accum
    int* deg     = (int*)(ws + off);   off += (size_t)N * 4;
    int* cursor  = (int*)(ws + off);   off += (size_t)N * 4;
    float* accum = (float*)(ws + off); off += 1024;
    size_t zbytes = off;
    float* dinv  = (float*)(ws + off); off += (size_t)N * 4;
    int* rowptr  = (int*)(ws + off);   off += ((size_t)N + 1) * 4;
    int* bsum    = (int*)(ws + off);   off += 2048;
    int* col     = (int*)(ws + off);   off += (size_t)E * 4;
    float* wgt   = (float*)(ws + off); off += (size_t)E * 4;
    float* h     = (float*)(ws + off); off += (size_t)N * D_HID * 4;
    float* agg   = (float*)(ws + off); off += (size_t)N * D_HID * 4;
    float* l     = (float*)(ws + off); off += (size_t)N * D_OUT * 4;
    float* s     = (float*)(ws + off); off += (size_t)N * 4;

    hipMemsetAsync(d_ws, 0, zbytes, stream);

    k_deg<<<(E + 255) / 256, 256, 0, stream>>>(edst, deg, E);
    k_dinv<<<(N + 255) / 256, 256, 0, stream>>>(deg, dinv, N);
    k_scanA<<<nb, 256, 0, stream>>>(deg, bsum, N);
    k_scanB<<<1, 512, 0, stream>>>(bsum, nb);
    k_scanC<<<nb, 256, 0, stream>>>(deg, bsum, rowptr, N);
    k_scatter<<<(E + 255) / 256, 256, 0, stream>>>(esrc, edst, rowptr, cursor, dinv, col, wgt, E);
    k_gemm1<<<(N + 63) / 64, 256, 0, stream>>>(x, W1, b1, h, N);
    k_spmm1_csr<<<(N + 3) / 4, 256, 0, stream>>>(rowptr, col, wgt, h, dinv, agg, N);
    k_bnstats<<<1024, 128, 0, stream>>>(agg, accum, N);
    k_bnfinal<<<1, 128, 0, stream>>>(accum, gamma, beta, 1.0f / (float)N);
    k_gemm2<<<(N + 63) / 64, 256, 0, stream>>>(agg, Wmu, bmu, accum, l, s, N);
    k_spmm2_csr<<<(N + 3) / 4, 256, 0, stream>>>(rowptr, col, wgt, l, s, dinv, noise, mu, lsd, zeta, N);
}

// Round 3
// 536.417 us; speedup vs baseline: 4.5292x; 1.7072x over previous
//
#include <hip/hip_runtime.h>
#include <hip/hip_bf16.h>
#include <math.h>

#define D_IN 128
#define D_HID 128
#define D_OUT 64
#define BN_EPS 1e-5f
#define SLOPE 0.01f
#define NSCALE 1.8f

typedef __attribute__((ext_vector_type(8))) short short8;
typedef __attribute__((ext_vector_type(4))) float f32x4;

__device__ inline void atomAddF(float* p, float v) {
#if defined(__gfx90a__) || defined(__gfx942__) || defined(__gfx950__)
    unsafeAtomicAdd(p, v);
#else
    atomicAdd(p, v);
#endif
}

__device__ inline ushort f2bf(float f) {  // RNE
    union { float f; uint u; } v; v.f = f;
    uint r = v.u + 0x7fff + ((v.u >> 16) & 1);
    return (ushort)(r >> 16);
}
__device__ inline float bf2f(ushort b) {
    union { uint u; float f; } v; v.u = ((uint)b) << 16;
    return v.f;
}

__global__ void k_deg(const int* __restrict__ dst, int* __restrict__ deg, int E) {
    int e = blockIdx.x * blockDim.x + threadIdx.x;
    if (e < E) atomicAdd(&deg[dst[e]], 1);
}

__global__ void k_dinv(const int* __restrict__ deg, float* __restrict__ dinv, int n) {
    int i = blockIdx.x * blockDim.x + threadIdx.x;
    if (i < n) dinv[i] = rsqrtf((float)deg[i] + 1.0f);
}

// --- scan: rowptr = exclusive_prefix(deg) -------------------------------
__global__ void k_scanA(const int* __restrict__ deg, int* __restrict__ bsum, int n) {
    __shared__ int sh[256];
    int i = blockIdx.x * 256 + threadIdx.x;
    sh[threadIdx.x] = (i < n) ? deg[i] : 0;
    __syncthreads();
    for (int off = 128; off >= 1; off >>= 1) {
        if (threadIdx.x < off) sh[threadIdx.x] += sh[threadIdx.x + off];
        __syncthreads();
    }
    if (threadIdx.x == 0) bsum[blockIdx.x] = sh[0];
}

__global__ void k_scanB(int* __restrict__ bsum, int nb) {  // single block, nb <= 512
    __shared__ int sh[512];
    int v = (threadIdx.x < nb) ? bsum[threadIdx.x] : 0;
    sh[threadIdx.x] = v;
    __syncthreads();
    for (int off = 1; off < 512; off <<= 1) {
        int t = (threadIdx.x >= off) ? sh[threadIdx.x - off] : 0;
        __syncthreads();
        sh[threadIdx.x] += t;
        __syncthreads();
    }
    if (threadIdx.x < nb) bsum[threadIdx.x] = sh[threadIdx.x] - v;  // exclusive
}

__global__ void k_scanC(const int* __restrict__ deg, const int* __restrict__ bsum,
                        int* __restrict__ rowptr, int n) {
    __shared__ int sh[256];
    int i = blockIdx.x * 256 + threadIdx.x;
    int v = (i < n) ? deg[i] : 0;
    sh[threadIdx.x] = v;
    __syncthreads();
    for (int off = 1; off < 256; off <<= 1) {
        int t = (threadIdx.x >= off) ? sh[threadIdx.x - off] : 0;
        __syncthreads();
        sh[threadIdx.x] += t;
        __syncthreads();
    }
    int excl = sh[threadIdx.x] - v + bsum[blockIdx.x];
    if (i < n) rowptr[i] = excl;
    if (i == n - 1) rowptr[n] = excl + v;
}

__global__ void k_scatter(const int* __restrict__ src, const int* __restrict__ dst,
                          const int* __restrict__ rowptr, int* __restrict__ cursor,
                          const float* __restrict__ dinv, int* __restrict__ col,
                          float* __restrict__ wgt, int E) {
    int e = blockIdx.x * blockDim.x + threadIdx.x;
    if (e >= E) return;
    int d = dst[e], s = src[e];
    int p = rowptr[d] + atomicAdd(&cursor[d], 1);
    col[p] = s;
    wgt[p] = dinv[s] * dinv[d];
}

// h_bf = bf16(x @ W1 + b1). Split-bf16 MFMA (hi/lo), W1 fragments staged in LDS.
// One wave computes 16 rows x 128 cols. 16x16x32 mfma:
//   A: row=lane&15, k=(lane>>4)*8+j ; B: col=lane&15, k=(lane>>4)*8+j
//   D: col=lane&15, row=(lane>>4)*4+reg
__global__ __launch_bounds__(256) void k_gemm1_mfma(const float* __restrict__ x,
        const float* __restrict__ W1, const float* __restrict__ b1,
        ushort* __restrict__ h_bf, int n, int nwt) {
    __shared__ ushort wf[2][4][8][64][8];  // [hi/lo][kt][ct][lane][j] = 64KB
    int t = threadIdx.x;
    for (int i = t; i < 16384; i += 256) {
        int k = i >> 7, nn = i & 127;
        float v = W1[i];
        ushort hi = f2bf(v);
        ushort lo = f2bf(v - bf2f(hi));
        int kt = k >> 5, ct = nn >> 4;
        int lane = ((k >> 3) & 3) * 16 + (nn & 15);
        int j = k & 7;
        wf[0][kt][ct][lane][j] = hi;
        wf[1][kt][ct][lane][j] = lo;
    }
    __syncthreads();
    int wid = t >> 6, lane = t & 63;
    int lrow = lane & 15, lkg = lane >> 4;
    float bias[8];
#pragma unroll
    for (int ct = 0; ct < 8; ++ct) bias[ct] = b1[ct * 16 + lrow];
    int stride = gridDim.x * 4;
    for (int wt = blockIdx.x * 4 + wid; wt < nwt; wt += stride) {
        size_t r0 = (size_t)wt * 16;
        int rr = (int)r0 + lrow;
        if (rr >= n) rr = n - 1;
        short8 ah[4], al[4];
#pragma unroll
        for (int kt = 0; kt < 4; ++kt) {
            const float* p = x + (size_t)rr * 128 + kt * 32 + lkg * 8;
            float va[8];
            *(f32x4*)&va[0] = *(const f32x4*)p;
            *(f32x4*)&va[4] = *(const f32x4*)(p + 4);
#pragma unroll
            for (int j = 0; j < 8; ++j) {
                ushort hb = f2bf(va[j]);
                ah[kt][j] = (short)hb;
                al[kt][j] = (short)f2bf(va[j] - bf2f(hb));
            }
        }
        f32x4 acc[8];
#pragma unroll
        for (int ct = 0; ct < 8; ++ct) {
            float bb = bias[ct];
            acc[ct][0] = bb; acc[ct][1] = bb; acc[ct][2] = bb; acc[ct][3] = bb;
        }
#pragma unroll
        for (int kt = 0; kt < 4; ++kt) {
#pragma unroll
            for (int ct = 0; ct < 8; ++ct) {
                short8 wh = *(const short8*)&wf[0][kt][ct][lane][0];
                short8 wl = *(const short8*)&wf[1][kt][ct][lane][0];
                acc[ct] = __builtin_amdgcn_mfma_f32_16x16x32_bf16(ah[kt], wh, acc[ct], 0, 0, 0);
                acc[ct] = __builtin_amdgcn_mfma_f32_16x16x32_bf16(al[kt], wh, acc[ct], 0, 0, 0);
                acc[ct] = __builtin_amdgcn_mfma_f32_16x16x32_bf16(ah[kt], wl, acc[ct], 0, 0, 0);
            }
        }
#pragma unroll
        for (int j = 0; j < 4; ++j) {
            int row = (int)r0 + lkg * 4 + j;
            if (row < n) {
#pragma unroll
                for (int ct = 0; ct < 8; ++ct)
                    h_bf[(size_t)row * 128 + ct * 16 + lrow] = f2bf(acc[ct][j]);
            }
        }
    }
}

// pull SpMM1 (bf16 gathers): agg[d] = sum_in h[src]*w + h[d]*dinv^2 (fp32 out)
__global__ __launch_bounds__(256) void k_spmm1_csr(const int* __restrict__ rowptr,
        const int* __restrict__ col, const float* __restrict__ wgt,
        const ushort* __restrict__ h_bf, const float* __restrict__ dinv,
        float* __restrict__ agg, int n) {
    int node = (blockIdx.x << 2) + (threadIdx.x >> 6);
    if (node >= n) return;
    int lane = threadIdx.x & 63;
    int beg = rowptr[node], end = rowptr[node + 1];
    float di = dinv[node];
    float slw = di * di;
    const uint* hb = (const uint*)h_bf;
    uint sv = hb[(size_t)node * 64 + lane];
    float2 acc;
    acc.x = bf2f((ushort)(sv & 0xffff)) * slw;
    acc.y = bf2f((ushort)(sv >> 16)) * slw;
    int p = beg;
    for (; p + 1 < end; p += 2) {
        int c0 = col[p], c1 = col[p + 1];
        float w0 = wgt[p], w1 = wgt[p + 1];
        uint v0 = hb[(size_t)c0 * 64 + lane];
        uint v1 = hb[(size_t)c1 * 64 + lane];
        acc.x = fmaf(bf2f((ushort)(v0 & 0xffff)), w0, acc.x);
        acc.y = fmaf(bf2f((ushort)(v0 >> 16)), w0, acc.y);
        acc.x = fmaf(bf2f((ushort)(v1 & 0xffff)), w1, acc.x);
        acc.y = fmaf(bf2f((ushort)(v1 >> 16)), w1, acc.y);
    }
    if (p < end) {
        int c = col[p];
        float w = wgt[p];
        uint v = hb[(size_t)c * 64 + lane];
        acc.x = fmaf(bf2f((ushort)(v & 0xffff)), w, acc.x);
        acc.y = fmaf(bf2f((ushort)(v >> 16)), w, acc.y);
    }
    ((float2*)(agg + (size_t)node * D_HID))[lane] = acc;
}

__global__ __launch_bounds__(128) void k_bnstats(const float* __restrict__ agg,
        float* __restrict__ accum, int n) {
    int col = threadIdx.x;
    float sum = 0.f, sq = 0.f;
    for (int r = blockIdx.x; r < n; r += gridDim.x) {
        float v = agg[(size_t)r * D_HID + col];
        sum += v;
        sq += v * v;
    }
    atomAddF(&accum[col], sum);
    atomAddF(&accum[D_HID + col], sq);
}

__global__ void k_bnfinal(float* __restrict__ accum, const float* __restrict__ gamma,
        const float* __restrict__ beta, float inv_n) {
    int c = threadIdx.x;
    float mean = accum[c] * inv_n;
    float var = accum[D_HID + c] * inv_n - mean * mean;
    float sc = gamma[c] * rsqrtf(var + BN_EPS);
    accum[c] = sc;
    accum[D_HID + c] = beta[c] - mean * sc;
}

// l_bf = bf16(lrelu(bn(agg)) @ Wmu + bmu), s = 1.8/max(||l||,1e-12). MFMA as gemm1.
__global__ __launch_bounds__(256) void k_gemm2_mfma(const float* __restrict__ agg,
        const float* __restrict__ Wmu, const float* __restrict__ bmu,
        const float* __restrict__ accum, ushort* __restrict__ l_bf,
        float* __restrict__ sOut, int n, int nwt) {
    __shared__ ushort wf[2][4][4][64][8];  // 32KB
    __shared__ float scs[D_HID], shs[D_HID];
    int t = threadIdx.x;
    for (int i = t; i < 8192; i += 256) {
        int k = i >> 6, nn = i & 63;
        float v = Wmu[i];
        ushort hi = f2bf(v);
        ushort lo = f2bf(v - bf2f(hi));
        int kt = k >> 5, ct = nn >> 4;
        int lane = ((k >> 3) & 3) * 16 + (nn & 15);
        int j = k & 7;
        wf[0][kt][ct][lane][j] = hi;
        wf[1][kt][ct][lane][j] = lo;
    }
    for (int i = t; i < D_HID; i += 256) {
        scs[i] = accum[i];
        shs[i] = accum[D_HID + i];
    }
    __syncthreads();
    int wid = t >> 6, lane = t & 63;
    int lrow = lane & 15, lkg = lane >> 4;
    float bias[4];
#pragma unroll
    for (int ct = 0; ct < 4; ++ct) bias[ct] = bmu[ct * 16 + lrow];
    int stride = gridDim.x * 4;
    for (int wt = blockIdx.x * 4 + wid; wt < nwt; wt += stride) {
        size_t r0 = (size_t)wt * 16;
        int rr = (int)r0 + lrow;
        if (rr >= n) rr = n - 1;
        short8 ah[4], al[4];
#pragma unroll
        for (int kt = 0; kt < 4; ++kt) {
            const float* p = agg + (size_t)rr * 128 + kt * 32 + lkg * 8;
            float va[8];
            *(f32x4*)&va[0] = *(const f32x4*)p;
            *(f32x4*)&va[4] = *(const f32x4*)(p + 4);
#pragma unroll
            for (int j = 0; j < 8; ++j) {
                int k = kt * 32 + lkg * 8 + j;
                float v = va[j] * scs[k] + shs[k];
                v = v > 0.f ? v : SLOPE * v;
                ushort hb = f2bf(v);
                ah[kt][j] = (short)hb;
                al[kt][j] = (short)f2bf(v - bf2f(hb));
            }
        }
        f32x4 acc[4];
#pragma unroll
        for (int ct = 0; ct < 4; ++ct) {
            float bb = bias[ct];
            acc[ct][0] = bb; acc[ct][1] = bb; acc[ct][2] = bb; acc[ct][3] = bb;
        }
#pragma unroll
        for (int kt = 0; kt < 4; ++kt) {
#pragma unroll
            for (int ct = 0; ct < 4; ++ct) {
                short8 wh = *(const short8*)&wf[0][kt][ct][lane][0];
                short8 wl = *(const short8*)&wf[1][kt][ct][lane][0];
                acc[ct] = __builtin_amdgcn_mfma_f32_16x16x32_bf16(ah[kt], wh, acc[ct], 0, 0, 0);
                acc[ct] = __builtin_amdgcn_mfma_f32_16x16x32_bf16(al[kt], wh, acc[ct], 0, 0, 0);
                acc[ct] = __builtin_amdgcn_mfma_f32_16x16x32_bf16(ah[kt], wl, acc[ct], 0, 0, 0);
            }
        }
#pragma unroll
        for (int j = 0; j < 4; ++j) {
            float ss = acc[0][j] * acc[0][j];
#pragma unroll
            for (int ct = 1; ct < 4; ++ct) ss = fmaf(acc[ct][j], acc[ct][j], ss);
            ss += __shfl_xor(ss, 1, 64);
            ss += __shfl_xor(ss, 2, 64);
            ss += __shfl_xor(ss, 4, 64);
            ss += __shfl_xor(ss, 8, 64);
            float srow = NSCALE / fmaxf(sqrtf(ss), 1e-12f);
            int row = (int)r0 + lkg * 4 + j;
            if (row < n) {
#pragma unroll
                for (int ct = 0; ct < 4; ++ct)
                    l_bf[(size_t)row * 64 + ct * 16 + lrow] = f2bf(acc[ct][j]);
                if (lrow == 0) sOut[row] = srow;
            }
        }
    }
}

// pull SpMM2 (bf16 gathers) + self-loop + reparam
__global__ __launch_bounds__(256) void k_spmm2_csr(const int* __restrict__ rowptr,
        const int* __restrict__ col, const float* __restrict__ wgt,
        const ushort* __restrict__ l_bf, const float* __restrict__ s,
        const float* __restrict__ dinv, const float* __restrict__ noise,
        float* __restrict__ mu, float* __restrict__ lsd, float* __restrict__ zeta,
        int n) {
    int node = (blockIdx.x << 2) + (threadIdx.x >> 6);
    if (node >= n) return;
    int lane = threadIdx.x & 63;
    int beg = rowptr[node], end = rowptr[node + 1];
    float di = dinv[node];
    float slw = di * di;
    float lv = bf2f(l_bf[(size_t)node * 64 + lane]);
    float accm = lv * slw;
    float accl = lv * s[node] * slw;
    int p = beg;
    for (; p + 1 < end; p += 2) {
        int c0 = col[p], c1 = col[p + 1];
        float w0 = wgt[p], w1 = wgt[p + 1];
        float v0 = bf2f(l_bf[(size_t)c0 * 64 + lane]);
        float v1 = bf2f(l_bf[(size_t)c1 * 64 + lane]);
        float s0 = s[c0], s1 = s[c1];
        accm = fmaf(v0, w0, accm);
        accl = fmaf(v0 * s0, w0, accl);
        accm = fmaf(v1, w1, accm);
        accl = fmaf(v1 * s1, w1, accl);
    }
    if (p < end) {
        int c = col[p];
        float w = wgt[p];
        float v = bf2f(l_bf[(size_t)c * 64 + lane]);
        accm = fmaf(v, w, accm);
        accl = fmaf(v * s[c], w, accl);
    }
    size_t idx = (size_t)node * D_OUT + lane;
    mu[idx] = accm;
    lsd[idx] = accl;
    zeta[idx] = accm + noise[idx] * expf(accl);
}

extern "C" void kernel_launch(void* const* d_in, const int* in_sizes, int n_in,
                              void* d_out, int out_size, void* d_ws, size_t ws_size,
                              hipStream_t stream) {
    const float* x     = (const float*)d_in[0];
    const int*   esrc  = (const int*)d_in[1];
    const int*   edst  = (const int*)d_in[2];
    const float* W1    = (const float*)d_in[3];
    const float* b1    = (const float*)d_in[4];
    const float* gamma = (const float*)d_in[5];
    const float* beta  = (const float*)d_in[6];
    const float* Wmu   = (const float*)d_in[7];
    const float* bmu   = (const float*)d_in[8];
    const float* noise = (const float*)d_in[9];
    int N = in_sizes[0] / D_IN;
    int E = in_sizes[1];
    int nb = (N + 255) / 256;
    int nwt = (N + 15) / 16;

    float* out  = (float*)d_out;
    float* mu   = out;
    float* lsd  = out + (size_t)N * D_OUT;
    float* zeta = out + 2 * (size_t)N * D_OUT;

    char* ws = (char*)d_ws;
    size_t off = 0;
    int* deg     = (int*)(ws + off);   off += (size_t)N * 4;
    int* cursor  = (int*)(ws + off);   off += (size_t)N * 4;
    float* accum = (float*)(ws + off); off += 1024;
    size_t zbytes = off;
    float* dinv  = (float*)(ws + off); off += (size_t)N * 4;
    int* rowptr  = (int*)(ws + off);   off += ((size_t)N + 1) * 4;
    int* bsum    = (int*)(ws + off);   off += 2048;
    int* col     = (int*)(ws + off);   off += (size_t)E * 4;
    float* wgt   = (float*)(ws + off); off += (size_t)E * 4;
    ushort* h_bf = (ushort*)(ws + off); off += (size_t)N * D_HID * 2;
    float* agg   = (float*)(ws + off); off += (size_t)N * D_HID * 4;
    ushort* l_bf = (ushort*)(ws + off); off += (size_t)N * D_OUT * 2;
    float* s     = (float*)(ws + off); off += (size_t)N * 4;

    hipMemsetAsync(d_ws, 0, zbytes, stream);

    k_deg<<<(E + 255) / 256, 256, 0, stream>>>(edst, deg, E);
    k_dinv<<<(N + 255) / 256, 256, 0, stream>>>(deg, dinv, N);
    k_scanA<<<nb, 256, 0, stream>>>(deg, bsum, N);
    k_scanB<<<1, 512, 0, stream>>>(bsum, nb);
    k_scanC<<<nb, 256, 0, stream>>>(deg, bsum, rowptr, N);
    k_scatter<<<(E + 255) / 256, 256, 0, stream>>>(esrc, edst, rowptr, cursor, dinv, col, wgt, E);
    k_gemm1_mfma<<<512, 256, 0, stream>>>(x, W1, b1, h_bf, N, nwt);
    k_spmm1_csr<<<(N + 3) / 4, 256, 0, stream>>>(rowptr, col, wgt, h_bf, dinv, agg, N);
    k_bnstats<<<1024, 128, 0, stream>>>(agg, accum, N);
    k_bnfinal<<<1, 128, 0, stream>>>(accum, gamma, beta, 1.0f / (float)N);
    k_gemm2_mfma<<<512, 256, 0, stream>>>(agg, Wmu, bmu, accum, l_bf, s, N, nwt);
    k_spmm2_csr<<<(N + 3) / 4, 256, 0, stream>>>(rowptr, col, wgt, l_bf, s, dinv, noise, mu, lsd, zeta, N);
}

// Round 4
// 448.464 us; speedup vs baseline: 5.4174x; 1.1961x over previous
//
#include <hip/hip_runtime.h>
#include <hip/hip_bf16.h>
#include <math.h>

#define D_IN 128
#define D_HID 128
#define D_OUT 64
#define BN_EPS 1e-5f
#define SLOPE 0.01f
#define NSCALE 1.8f

typedef __attribute__((ext_vector_type(8))) short short8;
typedef __attribute__((ext_vector_type(4))) float f32x4;

__device__ inline void atomAddF(float* p, float v) {
#if defined(__gfx90a__) || defined(__gfx942__) || defined(__gfx950__)
    unsafeAtomicAdd(p, v);
#else
    atomicAdd(p, v);
#endif
}

__device__ inline ushort f2bf(float f) {  // RNE
    union { float f; uint u; } v; v.f = f;
    uint r = v.u + 0x7fff + ((v.u >> 16) & 1);
    return (ushort)(r >> 16);
}
__device__ inline float bf2f(ushort b) {
    union { uint u; float f; } v; v.u = ((uint)b) << 16;
    return v.f;
}

__global__ void k_deg(const int* __restrict__ dst, int* __restrict__ deg, int E) {
    int e = blockIdx.x * blockDim.x + threadIdx.x;
    if (e < E) atomicAdd(&deg[dst[e]], 1);
}

// --- scan: rowptr = exclusive_prefix(deg); also dinv = rsqrt(deg+1) -----
__global__ void k_scanA(const int* __restrict__ deg, int* __restrict__ bsum, int n) {
    __shared__ int sh[256];
    int i = blockIdx.x * 256 + threadIdx.x;
    sh[threadIdx.x] = (i < n) ? deg[i] : 0;
    __syncthreads();
    for (int off = 128; off >= 1; off >>= 1) {
        if (threadIdx.x < off) sh[threadIdx.x] += sh[threadIdx.x + off];
        __syncthreads();
    }
    if (threadIdx.x == 0) bsum[blockIdx.x] = sh[0];
}

__global__ void k_scanB(int* __restrict__ bsum, int nb) {  // single block, nb <= 512
    __shared__ int sh[512];
    int v = (threadIdx.x < nb) ? bsum[threadIdx.x] : 0;
    sh[threadIdx.x] = v;
    __syncthreads();
    for (int off = 1; off < 512; off <<= 1) {
        int t = (threadIdx.x >= off) ? sh[threadIdx.x - off] : 0;
        __syncthreads();
        sh[threadIdx.x] += t;
        __syncthreads();
    }
    if (threadIdx.x < nb) bsum[threadIdx.x] = sh[threadIdx.x] - v;  // exclusive
}

__global__ void k_scanC(const int* __restrict__ deg, const int* __restrict__ bsum,
                        int* __restrict__ rowptr, float* __restrict__ dinv, int n) {
    __shared__ int sh[256];
    int i = blockIdx.x * 256 + threadIdx.x;
    int v = (i < n) ? deg[i] : 0;
    sh[threadIdx.x] = v;
    __syncthreads();
    for (int off = 1; off < 256; off <<= 1) {
        int t = (threadIdx.x >= off) ? sh[threadIdx.x - off] : 0;
        __syncthreads();
        sh[threadIdx.x] += t;
        __syncthreads();
    }
    int excl = sh[threadIdx.x] - v + bsum[blockIdx.x];
    if (i < n) {
        rowptr[i] = excl;
        dinv[i] = rsqrtf((float)v + 1.0f);
    }
    if (i == n - 1) rowptr[n] = excl + v;
}

// scatter edges into CSR (by dst), packed (col, wgt) as int2 -> one 8B store
__global__ void k_scatter(const int* __restrict__ src, const int* __restrict__ dst,
                          const int* __restrict__ rowptr, int* __restrict__ cursor,
                          const float* __restrict__ dinv, int2* __restrict__ cw, int E) {
    int e = blockIdx.x * blockDim.x + threadIdx.x;
    if (e >= E) return;
    int d = dst[e], s = src[e];
    int p = rowptr[d] + atomicAdd(&cursor[d], 1);
    int2 v;
    v.x = s;
    v.y = __float_as_int(dinv[s] * dinv[d]);
    cw[p] = v;
}

// h_bf = bf16(x @ W1 + b1). Split-bf16 MFMA (hi/lo), W1 fragments staged in LDS.
__global__ __launch_bounds__(256) void k_gemm1_mfma(const float* __restrict__ x,
        const float* __restrict__ W1, const float* __restrict__ b1,
        ushort* __restrict__ h_bf, int n, int nwt) {
    __shared__ ushort wf[2][4][8][64][8];  // [hi/lo][kt][ct][lane][j] = 64KB
    int t = threadIdx.x;
    for (int i = t; i < 16384; i += 256) {
        int k = i >> 7, nn = i & 127;
        float v = W1[i];
        ushort hi = f2bf(v);
        ushort lo = f2bf(v - bf2f(hi));
        int kt = k >> 5, ct = nn >> 4;
        int lane = ((k >> 3) & 3) * 16 + (nn & 15);
        int j = k & 7;
        wf[0][kt][ct][lane][j] = hi;
        wf[1][kt][ct][lane][j] = lo;
    }
    __syncthreads();
    int wid = t >> 6, lane = t & 63;
    int lrow = lane & 15, lkg = lane >> 4;
    float bias[8];
#pragma unroll
    for (int ct = 0; ct < 8; ++ct) bias[ct] = b1[ct * 16 + lrow];
    int stride = gridDim.x * 4;
    for (int wt = blockIdx.x * 4 + wid; wt < nwt; wt += stride) {
        size_t r0 = (size_t)wt * 16;
        int rr = (int)r0 + lrow;
        if (rr >= n) rr = n - 1;
        short8 ah[4], al[4];
#pragma unroll
        for (int kt = 0; kt < 4; ++kt) {
            const float* p = x + (size_t)rr * 128 + kt * 32 + lkg * 8;
            float va[8];
            *(f32x4*)&va[0] = *(const f32x4*)p;
            *(f32x4*)&va[4] = *(const f32x4*)(p + 4);
#pragma unroll
            for (int j = 0; j < 8; ++j) {
                ushort hb = f2bf(va[j]);
                ah[kt][j] = (short)hb;
                al[kt][j] = (short)f2bf(va[j] - bf2f(hb));
            }
        }
        f32x4 acc[8];
#pragma unroll
        for (int ct = 0; ct < 8; ++ct) {
            float bb = bias[ct];
            acc[ct][0] = bb; acc[ct][1] = bb; acc[ct][2] = bb; acc[ct][3] = bb;
        }
#pragma unroll
        for (int kt = 0; kt < 4; ++kt) {
#pragma unroll
            for (int ct = 0; ct < 8; ++ct) {
                short8 wh = *(const short8*)&wf[0][kt][ct][lane][0];
                short8 wl = *(const short8*)&wf[1][kt][ct][lane][0];
                acc[ct] = __builtin_amdgcn_mfma_f32_16x16x32_bf16(ah[kt], wh, acc[ct], 0, 0, 0);
                acc[ct] = __builtin_amdgcn_mfma_f32_16x16x32_bf16(al[kt], wh, acc[ct], 0, 0, 0);
                acc[ct] = __builtin_amdgcn_mfma_f32_16x16x32_bf16(ah[kt], wl, acc[ct], 0, 0, 0);
            }
        }
#pragma unroll
        for (int j = 0; j < 4; ++j) {
            int row = (int)r0 + lkg * 4 + j;
            if (row < n) {
#pragma unroll
                for (int ct = 0; ct < 8; ++ct)
                    h_bf[(size_t)row * 128 + ct * 16 + lrow] = f2bf(acc[ct][j]);
            }
        }
    }
}

// pull SpMM1 (bf16 gathers) + fused BN partial stats; agg stored as packed bf16.
// grid-stride, 8 waves/block; lane owns cols {2*lane, 2*lane+1}
__global__ __launch_bounds__(512) void k_spmm1_csr(const int* __restrict__ rowptr,
        const int2* __restrict__ cw, const uint* __restrict__ hb,
        const float* __restrict__ dinv, uint* __restrict__ agg_bf,
        float* __restrict__ accum, int n) {
    __shared__ float red[512];
    int t = threadIdx.x;
    int wid = t >> 6, lane = t & 63;
    int gw = blockIdx.x * 8 + wid;
    int nw = gridDim.x * 8;
    float s0 = 0.f, s1 = 0.f, q0 = 0.f, q1 = 0.f;
    for (int node = gw; node < n; node += nw) {
        int beg = rowptr[node], end = rowptr[node + 1];
        float di = dinv[node];
        float slw = di * di;
        uint sv = hb[(size_t)node * 64 + lane];
        float ax = bf2f((ushort)(sv & 0xffff)) * slw;
        float ay = bf2f((ushort)(sv >> 16)) * slw;
        int p = beg;
        for (; p + 3 < end; p += 4) {
            int2 e0 = cw[p], e1 = cw[p + 1], e2 = cw[p + 2], e3 = cw[p + 3];
            uint v0 = hb[(size_t)e0.x * 64 + lane];
            uint v1 = hb[(size_t)e1.x * 64 + lane];
            uint v2 = hb[(size_t)e2.x * 64 + lane];
            uint v3 = hb[(size_t)e3.x * 64 + lane];
            float w0 = __int_as_float(e0.y), w1 = __int_as_float(e1.y);
            float w2 = __int_as_float(e2.y), w3 = __int_as_float(e3.y);
            ax = fmaf(bf2f((ushort)(v0 & 0xffff)), w0, ax);
            ay = fmaf(bf2f((ushort)(v0 >> 16)), w0, ay);
            ax = fmaf(bf2f((ushort)(v1 & 0xffff)), w1, ax);
            ay = fmaf(bf2f((ushort)(v1 >> 16)), w1, ay);
            ax = fmaf(bf2f((ushort)(v2 & 0xffff)), w2, ax);
            ay = fmaf(bf2f((ushort)(v2 >> 16)), w2, ay);
            ax = fmaf(bf2f((ushort)(v3 & 0xffff)), w3, ax);
            ay = fmaf(bf2f((ushort)(v3 >> 16)), w3, ay);
        }
        for (; p < end; ++p) {
            int2 e = cw[p];
            uint v = hb[(size_t)e.x * 64 + lane];
            float w = __int_as_float(e.y);
            ax = fmaf(bf2f((ushort)(v & 0xffff)), w, ax);
            ay = fmaf(bf2f((ushort)(v >> 16)), w, ay);
        }
        agg_bf[(size_t)node * 64 + lane] = ((uint)f2bf(ay) << 16) | (uint)f2bf(ax);
        s0 += ax; q0 = fmaf(ax, ax, q0);
        s1 += ay; q1 = fmaf(ay, ay, q1);
    }
    // cross-wave reduce (8 waves) then one atomic per column per block
    red[t] = s0; __syncthreads();
    if (t < 64) { float v = 0.f; for (int w = 0; w < 8; ++w) v += red[w * 64 + t];
        atomAddF(&accum[2 * t], v); }
    __syncthreads();
    red[t] = s1; __syncthreads();
    if (t < 64) { float v = 0.f; for (int w = 0; w < 8; ++w) v += red[w * 64 + t];
        atomAddF(&accum[2 * t + 1], v); }
    __syncthreads();
    red[t] = q0; __syncthreads();
    if (t < 64) { float v = 0.f; for (int w = 0; w < 8; ++w) v += red[w * 64 + t];
        atomAddF(&accum[128 + 2 * t], v); }
    __syncthreads();
    red[t] = q1; __syncthreads();
    if (t < 64) { float v = 0.f; for (int w = 0; w < 8; ++w) v += red[w * 64 + t];
        atomAddF(&accum[128 + 2 * t + 1], v); }
}

__global__ void k_bnfinal(float* __restrict__ accum, const float* __restrict__ gamma,
        const float* __restrict__ beta, float inv_n) {
    int c = threadIdx.x;
    float mean = accum[c] * inv_n;
    float var = accum[D_HID + c] * inv_n - mean * mean;
    float sc = gamma[c] * rsqrtf(var + BN_EPS);
    accum[c] = sc;
    accum[D_HID + c] = beta[c] - mean * sc;
}

// l_bf = bf16(lrelu(bn(agg_bf)) @ Wmu + bmu), s = 1.8/max(||l||,1e-12)
__global__ __launch_bounds__(256) void k_gemm2_mfma(const ushort* __restrict__ agg_bf,
        const float* __restrict__ Wmu, const float* __restrict__ bmu,
        const float* __restrict__ accum, ushort* __restrict__ l_bf,
        float* __restrict__ sOut, int n, int nwt) {
    __shared__ ushort wf[2][4][4][64][8];  // 32KB
    __shared__ float scs[D_HID], shs[D_HID];
    int t = threadIdx.x;
    for (int i = t; i < 8192; i += 256) {
        int k = i >> 6, nn = i & 63;
        float v = Wmu[i];
        ushort hi = f2bf(v);
        ushort lo = f2bf(v - bf2f(hi));
        int kt = k >> 5, ct = nn >> 4;
        int lane = ((k >> 3) & 3) * 16 + (nn & 15);
        int j = k & 7;
        wf[0][kt][ct][lane][j] = hi;
        wf[1][kt][ct][lane][j] = lo;
    }
    for (int i = t; i < D_HID; i += 256) {
        scs[i] = accum[i];
        shs[i] = accum[D_HID + i];
    }
    __syncthreads();
    int wid = t >> 6, lane = t & 63;
    int lrow = lane & 15, lkg = lane >> 4;
    float bias[4];
#pragma unroll
    for (int ct = 0; ct < 4; ++ct) bias[ct] = bmu[ct * 16 + lrow];
    int stride = gridDim.x * 4;
    for (int wt = blockIdx.x * 4 + wid; wt < nwt; wt += stride) {
        size_t r0 = (size_t)wt * 16;
        int rr = (int)r0 + lrow;
        if (rr >= n) rr = n - 1;
        short8 ah[4], al[4];
#pragma unroll
        for (int kt = 0; kt < 4; ++kt) {
            const ushort* p = agg_bf + (size_t)rr * 128 + kt * 32 + lkg * 8;
            short8 raw = *(const short8*)p;
#pragma unroll
            for (int j = 0; j < 8; ++j) {
                int k = kt * 32 + lkg * 8 + j;
                float v = bf2f((ushort)raw[j]) * scs[k] + shs[k];
                v = v > 0.f ? v : SLOPE * v;
                ushort hb = f2bf(v);
                ah[kt][j] = (short)hb;
                al[kt][j] = (short)f2bf(v - bf2f(hb));
            }
        }
        f32x4 acc[4];
#pragma unroll
        for (int ct = 0; ct < 4; ++ct) {
            float bb = bias[ct];
            acc[ct][0] = bb; acc[ct][1] = bb; acc[ct][2] = bb; acc[ct][3] = bb;
        }
#pragma unroll
        for (int kt = 0; kt < 4; ++kt) {
#pragma unroll
            for (int ct = 0; ct < 4; ++ct) {
                short8 wh = *(const short8*)&wf[0][kt][ct][lane][0];
                short8 wl = *(const short8*)&wf[1][kt][ct][lane][0];
                acc[ct] = __builtin_amdgcn_mfma_f32_16x16x32_bf16(ah[kt], wh, acc[ct], 0, 0, 0);
                acc[ct] = __builtin_amdgcn_mfma_f32_16x16x32_bf16(al[kt], wh, acc[ct], 0, 0, 0);
                acc[ct] = __builtin_amdgcn_mfma_f32_16x16x32_bf16(ah[kt], wl, acc[ct], 0, 0, 0);
            }
        }
#pragma unroll
        for (int j = 0; j < 4; ++j) {
            float ss = acc[0][j] * acc[0][j];
#pragma unroll
            for (int ct = 1; ct < 4; ++ct) ss = fmaf(acc[ct][j], acc[ct][j], ss);
            ss += __shfl_xor(ss, 1, 64);
            ss += __shfl_xor(ss, 2, 64);
            ss += __shfl_xor(ss, 4, 64);
            ss += __shfl_xor(ss, 8, 64);
            float srow = NSCALE / fmaxf(sqrtf(ss), 1e-12f);
            int row = (int)r0 + lkg * 4 + j;
            if (row < n) {
#pragma unroll
                for (int ct = 0; ct < 4; ++ct)
                    l_bf[(size_t)row * 64 + ct * 16 + lrow] = f2bf(acc[ct][j]);
                if (lrow == 0) sOut[row] = srow;
            }
        }
    }
}

// pull SpMM2 (bf16 gathers, x4 unroll) + self-loop + reparam
__global__ __launch_bounds__(256) void k_spmm2_csr(const int* __restrict__ rowptr,
        const int2* __restrict__ cw, const ushort* __restrict__ l_bf,
        const float* __restrict__ s, const float* __restrict__ dinv,
        const float* __restrict__ noise, float* __restrict__ mu,
        float* __restrict__ lsd, float* __restrict__ zeta, int n) {
    int node = (blockIdx.x << 2) + (threadIdx.x >> 6);
    if (node >= n) return;
    int lane = threadIdx.x & 63;
    int beg = rowptr[node], end = rowptr[node + 1];
    float di = dinv[node];
    float slw = di * di;
    float lv = bf2f(l_bf[(size_t)node * 64 + lane]);
    float accm = lv * slw;
    float accl = lv * s[node] * slw;
    int p = beg;
    for (; p + 3 < end; p += 4) {
        int2 e0 = cw[p], e1 = cw[p + 1], e2 = cw[p + 2], e3 = cw[p + 3];
        float v0 = bf2f(l_bf[(size_t)e0.x * 64 + lane]);
        float v1 = bf2f(l_bf[(size_t)e1.x * 64 + lane]);
        float v2 = bf2f(l_bf[(size_t)e2.x * 64 + lane]);
        float v3 = bf2f(l_bf[(size_t)e3.x * 64 + lane]);
        float s0 = s[e0.x], s1 = s[e1.x], s2 = s[e2.x], s3 = s[e3.x];
        float w0 = __int_as_float(e0.y), w1 = __int_as_float(e1.y);
        float w2 = __int_as_float(e2.y), w3 = __int_as_float(e3.y);
        accm = fmaf(v0, w0, accm); accl = fmaf(v0 * s0, w0, accl);
        accm = fmaf(v1, w1, accm); accl = fmaf(v1 * s1, w1, accl);
        accm = fmaf(v2, w2, accm); accl = fmaf(v2 * s2, w2, accl);
        accm = fmaf(v3, w3, accm); accl = fmaf(v3 * s3, w3, accl);
    }
    for (; p < end; ++p) {
        int2 e = cw[p];
        float v = bf2f(l_bf[(size_t)e.x * 64 + lane]);
        float w = __int_as_float(e.y);
        accm = fmaf(v, w, accm);
        accl = fmaf(v * s[e.x], w, accl);
    }
    size_t idx = (size_t)node * D_OUT + lane;
    mu[idx] = accm;
    lsd[idx] = accl;
    zeta[idx] = accm + noise[idx] * expf(accl);
}

extern "C" void kernel_launch(void* const* d_in, const int* in_sizes, int n_in,
                              void* d_out, int out_size, void* d_ws, size_t ws_size,
                              hipStream_t stream) {
    const float* x     = (const float*)d_in[0];
    const int*   esrc  = (const int*)d_in[1];
    const int*   edst  = (const int*)d_in[2];
    const float* W1    = (const float*)d_in[3];
    const float* b1    = (const float*)d_in[4];
    const float* gamma = (const float*)d_in[5];
    const float* beta  = (const float*)d_in[6];
    const float* Wmu   = (const float*)d_in[7];
    const float* bmu   = (const float*)d_in[8];
    const float* noise = (const float*)d_in[9];
    int N = in_sizes[0] / D_IN;
    int E = in_sizes[1];
    int nb = (N + 255) / 256;
    int nwt = (N + 15) / 16;

    float* out  = (float*)d_out;
    float* mu   = out;
    float* lsd  = out + (size_t)N * D_OUT;
    float* zeta = out + 2 * (size_t)N * D_OUT;

    char* ws = (char*)d_ws;
    size_t off = 0;
    auto alloc = [&](size_t bytes) {
        void* p = ws + off;
        off += (bytes + 255) & ~(size_t)255;
        return p;
    };
    int* deg      = (int*)alloc((size_t)N * 4);
    int* cursor   = (int*)alloc((size_t)N * 4);
    float* accum  = (float*)alloc(1024);
    size_t zbytes = off;  // deg + cursor + accum zeroed
    float* dinv   = (float*)alloc((size_t)N * 4);
    int* rowptr   = (int*)alloc(((size_t)N + 1) * 4);
    int* bsum     = (int*)alloc(2048);
    int2* cw      = (int2*)alloc((size_t)E * 8);
    ushort* h_bf  = (ushort*)alloc((size_t)N * D_HID * 2);
    uint* agg_bf  = (uint*)alloc((size_t)N * (D_HID / 2) * 4);
    ushort* l_bf  = (ushort*)alloc((size_t)N * D_OUT * 2);
    float* s      = (float*)alloc((size_t)N * 4);

    hipMemsetAsync(d_ws, 0, zbytes, stream);

    k_deg<<<(E + 255) / 256, 256, 0, stream>>>(edst, deg, E);
    k_scanA<<<nb, 256, 0, stream>>>(deg, bsum, N);
    k_scanB<<<1, 512, 0, stream>>>(bsum, nb);
    k_scanC<<<nb, 256, 0, stream>>>(deg, bsum, rowptr, dinv, N);
    k_scatter<<<(E + 255) / 256, 256, 0, stream>>>(esrc, edst, rowptr, cursor, dinv, cw, E);
    k_gemm1_mfma<<<512, 256, 0, stream>>>(x, W1, b1, h_bf, N, nwt);
    k_spmm1_csr<<<1024, 512, 0, stream>>>(rowptr, cw, (const uint*)h_bf, dinv, agg_bf, accum, N);
    k_bnfinal<<<1, 128, 0, stream>>>(accum, gamma, beta, 1.0f / (float)N);
    k_gemm2_mfma<<<512, 256, 0, stream>>>((const ushort*)agg_bf, Wmu, bmu, accum, l_bf, s, N, nwt);
    k_spmm2_csr<<<(N + 3) / 4, 256, 0, stream>>>(rowptr, cw, l_bf, s, dinv, noise, mu, lsd, zeta, N);
}

// Round 5
// 412.845 us; speedup vs baseline: 5.8849x; 1.0863x over previous
//
#include <hip/hip_runtime.h>
#include <hip/hip_bf16.h>
#include <math.h>

#define D_IN 128
#define D_HID 128
#define D_OUT 64
#define BN_EPS 1e-5f
#define SLOPE 0.01f
#define NSCALE 1.8f

typedef __attribute__((ext_vector_type(8))) short short8;
typedef __attribute__((ext_vector_type(4))) float f32x4;

__device__ inline void atomAddF(float* p, float v) {
#if defined(__gfx90a__) || defined(__gfx942__) || defined(__gfx950__)
    unsafeAtomicAdd(p, v);
#else
    atomicAdd(p, v);
#endif
}

__device__ inline ushort f2bf(float f) {  // RNE
    union { float f; uint u; } v; v.f = f;
    uint r = v.u + 0x7fff + ((v.u >> 16) & 1);
    return (ushort)(r >> 16);
}
__device__ inline float bf2f(ushort b) {
    union { uint u; float f; } v; v.u = ((uint)b) << 16;
    return v.f;
}

__global__ void k_deg(const int* __restrict__ dst, int* __restrict__ deg, int E) {
    int e = blockIdx.x * blockDim.x + threadIdx.x;
    if (e < E) atomicAdd(&deg[dst[e]], 1);
}

// --- scan: rowptr = exclusive_prefix(deg); also dinv = rsqrt(deg+1) -----
__global__ void k_scanA(const int* __restrict__ deg, int* __restrict__ bsum, int n) {
    __shared__ int sh[256];
    int i = blockIdx.x * 256 + threadIdx.x;
    sh[threadIdx.x] = (i < n) ? deg[i] : 0;
    __syncthreads();
    for (int off = 128; off >= 1; off >>= 1) {
        if (threadIdx.x < off) sh[threadIdx.x] += sh[threadIdx.x + off];
        __syncthreads();
    }
    if (threadIdx.x == 0) bsum[blockIdx.x] = sh[0];
}

__global__ void k_scanB(int* __restrict__ bsum, int nb) {  // single block, nb <= 512
    __shared__ int sh[512];
    int v = (threadIdx.x < nb) ? bsum[threadIdx.x] : 0;
    sh[threadIdx.x] = v;
    __syncthreads();
    for (int off = 1; off < 512; off <<= 1) {
        int t = (threadIdx.x >= off) ? sh[threadIdx.x - off] : 0;
        __syncthreads();
        sh[threadIdx.x] += t;
        __syncthreads();
    }
    if (threadIdx.x < nb) bsum[threadIdx.x] = sh[threadIdx.x] - v;  // exclusive
}

__global__ void k_scanC(const int* __restrict__ deg, const int* __restrict__ bsum,
                        int* __restrict__ rowptr, float* __restrict__ dinv, int n) {
    __shared__ int sh[256];
    int i = blockIdx.x * 256 + threadIdx.x;
    int v = (i < n) ? deg[i] : 0;
    sh[threadIdx.x] = v;
    __syncthreads();
    for (int off = 1; off < 256; off <<= 1) {
        int t = (threadIdx.x >= off) ? sh[threadIdx.x - off] : 0;
        __syncthreads();
        sh[threadIdx.x] += t;
        __syncthreads();
    }
    int excl = sh[threadIdx.x] - v + bsum[blockIdx.x];
    if (i < n) {
        rowptr[i] = excl;
        dinv[i] = rsqrtf((float)v + 1.0f);
    }
    if (i == n - 1) rowptr[n] = excl + v;
}

// scatter edges into CSR (by dst), packed (col, wgt) as int2 -> one 8B store
__global__ void k_scatter(const int* __restrict__ src, const int* __restrict__ dst,
                          const int* __restrict__ rowptr, int* __restrict__ cursor,
                          const float* __restrict__ dinv, int2* __restrict__ cw, int E) {
    int e = blockIdx.x * blockDim.x + threadIdx.x;
    if (e >= E) return;
    int d = dst[e], s = src[e];
    int p = rowptr[d] + atomicAdd(&cursor[d], 1);
    int2 v;
    v.x = s;
    v.y = __float_as_int(dinv[s] * dinv[d]);
    cw[p] = v;
}

// h_bf = bf16(x @ W1 + b1). Split-bf16 MFMA (hi/lo), W1 fragments staged in LDS.
__global__ __launch_bounds__(256) void k_gemm1_mfma(const float* __restrict__ x,
        const float* __restrict__ W1, const float* __restrict__ b1,
        ushort* __restrict__ h_bf, int n, int nwt) {
    __shared__ ushort wf[2][4][8][64][8];  // [hi/lo][kt][ct][lane][j] = 64KB
    int t = threadIdx.x;
    for (int i = t; i < 16384; i += 256) {
        int k = i >> 7, nn = i & 127;
        float v = W1[i];
        ushort hi = f2bf(v);
        ushort lo = f2bf(v - bf2f(hi));
        int kt = k >> 5, ct = nn >> 4;
        int lane = ((k >> 3) & 3) * 16 + (nn & 15);
        int j = k & 7;
        wf[0][kt][ct][lane][j] = hi;
        wf[1][kt][ct][lane][j] = lo;
    }
    __syncthreads();
    int wid = t >> 6, lane = t & 63;
    int lrow = lane & 15, lkg = lane >> 4;
    float bias[8];
#pragma unroll
    for (int ct = 0; ct < 8; ++ct) bias[ct] = b1[ct * 16 + lrow];
    int stride = gridDim.x * 4;
    for (int wt = blockIdx.x * 4 + wid; wt < nwt; wt += stride) {
        size_t r0 = (size_t)wt * 16;
        int rr = (int)r0 + lrow;
        if (rr >= n) rr = n - 1;
        short8 ah[4], al[4];
#pragma unroll
        for (int kt = 0; kt < 4; ++kt) {
            const float* p = x + (size_t)rr * 128 + kt * 32 + lkg * 8;
            float va[8];
            *(f32x4*)&va[0] = *(const f32x4*)p;
            *(f32x4*)&va[4] = *(const f32x4*)(p + 4);
#pragma unroll
            for (int j = 0; j < 8; ++j) {
                ushort hb = f2bf(va[j]);
                ah[kt][j] = (short)hb;
                al[kt][j] = (short)f2bf(va[j] - bf2f(hb));
            }
        }
        f32x4 acc[8];
#pragma unroll
        for (int ct = 0; ct < 8; ++ct) {
            float bb = bias[ct];
            acc[ct][0] = bb; acc[ct][1] = bb; acc[ct][2] = bb; acc[ct][3] = bb;
        }
#pragma unroll
        for (int kt = 0; kt < 4; ++kt) {
#pragma unroll
            for (int ct = 0; ct < 8; ++ct) {
                short8 wh = *(const short8*)&wf[0][kt][ct][lane][0];
                short8 wl = *(const short8*)&wf[1][kt][ct][lane][0];
                acc[ct] = __builtin_amdgcn_mfma_f32_16x16x32_bf16(ah[kt], wh, acc[ct], 0, 0, 0);
                acc[ct] = __builtin_amdgcn_mfma_f32_16x16x32_bf16(al[kt], wh, acc[ct], 0, 0, 0);
                acc[ct] = __builtin_amdgcn_mfma_f32_16x16x32_bf16(ah[kt], wl, acc[ct], 0, 0, 0);
            }
        }
#pragma unroll
        for (int j = 0; j < 4; ++j) {
            int row = (int)r0 + lkg * 4 + j;
            if (row < n) {
#pragma unroll
                for (int ct = 0; ct < 8; ++ct)
                    h_bf[(size_t)row * 128 + ct * 16 + lrow] = f2bf(acc[ct][j]);
            }
        }
    }
}

// pull SpMM1, split-wave: 2 edges/wave (half-wave each, 32 lanes x uint2 = 256B row),
// x4 unrolled pairs = 8 edges in flight. Fused BN partial stats. agg packed bf16.
__global__ __launch_bounds__(512) void k_spmm1_csr(const int* __restrict__ rowptr,
        const int2* __restrict__ cw, const uint2* __restrict__ hb2,
        const float* __restrict__ dinv, uint2* __restrict__ agg_bf,
        float* __restrict__ accum, int n) {
    __shared__ float red[8][32][4];
    int t = threadIdx.x;
    int wid = t >> 6, lane = t & 63;
    int half = lane >> 5, g = lane & 31;
    int gw = blockIdx.x * 8 + wid;
    int nw = gridDim.x * 8;
    float sx[4] = {0.f, 0.f, 0.f, 0.f}, sq[4] = {0.f, 0.f, 0.f, 0.f};
    for (int node = gw; node < n; node += nw) {
        int beg = rowptr[node], end = rowptr[node + 1];
        float a0 = 0.f, a1 = 0.f, a2 = 0.f, a3 = 0.f;
        if (half == 0) {  // self-loop on half 0
            float di = dinv[node];
            float slw = di * di;
            uint2 sv = hb2[(size_t)node * 32 + g];
            a0 = bf2f((ushort)(sv.x & 0xffff)) * slw;
            a1 = bf2f((ushort)(sv.x >> 16)) * slw;
            a2 = bf2f((ushort)(sv.y & 0xffff)) * slw;
            a3 = bf2f((ushort)(sv.y >> 16)) * slw;
        }
        int p = beg;
        for (; p + 8 <= end; p += 8) {
            int2 e0 = cw[p + half], e1 = cw[p + 2 + half];
            int2 e2 = cw[p + 4 + half], e3 = cw[p + 6 + half];
            uint2 v0 = hb2[(size_t)e0.x * 32 + g];
            uint2 v1 = hb2[(size_t)e1.x * 32 + g];
            uint2 v2 = hb2[(size_t)e2.x * 32 + g];
            uint2 v3 = hb2[(size_t)e3.x * 32 + g];
            float w0 = __int_as_float(e0.y), w1 = __int_as_float(e1.y);
            float w2 = __int_as_float(e2.y), w3 = __int_as_float(e3.y);
            a0 = fmaf(bf2f((ushort)(v0.x & 0xffff)), w0, a0);
            a1 = fmaf(bf2f((ushort)(v0.x >> 16)), w0, a1);
            a2 = fmaf(bf2f((ushort)(v0.y & 0xffff)), w0, a2);
            a3 = fmaf(bf2f((ushort)(v0.y >> 16)), w0, a3);
            a0 = fmaf(bf2f((ushort)(v1.x & 0xffff)), w1, a0);
            a1 = fmaf(bf2f((ushort)(v1.x >> 16)), w1, a1);
            a2 = fmaf(bf2f((ushort)(v1.y & 0xffff)), w1, a2);
            a3 = fmaf(bf2f((ushort)(v1.y >> 16)), w1, a3);
            a0 = fmaf(bf2f((ushort)(v2.x & 0xffff)), w2, a0);
            a1 = fmaf(bf2f((ushort)(v2.x >> 16)), w2, a1);
            a2 = fmaf(bf2f((ushort)(v2.y & 0xffff)), w2, a2);
            a3 = fmaf(bf2f((ushort)(v2.y >> 16)), w2, a3);
            a0 = fmaf(bf2f((ushort)(v3.x & 0xffff)), w3, a0);
            a1 = fmaf(bf2f((ushort)(v3.x >> 16)), w3, a1);
            a2 = fmaf(bf2f((ushort)(v3.y & 0xffff)), w3, a2);
            a3 = fmaf(bf2f((ushort)(v3.y >> 16)), w3, a3);
        }
        for (; p < end; p += 2) {
            int idx = p + half;
            int2 e = cw[(idx < end) ? idx : (end - 1)];
            float w = (idx < end) ? __int_as_float(e.y) : 0.f;
            uint2 v = hb2[(size_t)e.x * 32 + g];
            a0 = fmaf(bf2f((ushort)(v.x & 0xffff)), w, a0);
            a1 = fmaf(bf2f((ushort)(v.x >> 16)), w, a1);
            a2 = fmaf(bf2f((ushort)(v.y & 0xffff)), w, a2);
            a3 = fmaf(bf2f((ushort)(v.y >> 16)), w, a3);
        }
        // combine halves
        a0 += __shfl_xor(a0, 32, 64);
        a1 += __shfl_xor(a1, 32, 64);
        a2 += __shfl_xor(a2, 32, 64);
        a3 += __shfl_xor(a3, 32, 64);
        if (half == 0) {
            uint2 pk;
            pk.x = ((uint)f2bf(a1) << 16) | (uint)f2bf(a0);
            pk.y = ((uint)f2bf(a3) << 16) | (uint)f2bf(a2);
            agg_bf[(size_t)node * 32 + g] = pk;
            sx[0] += a0; sq[0] = fmaf(a0, a0, sq[0]);
            sx[1] += a1; sq[1] = fmaf(a1, a1, sq[1]);
            sx[2] += a2; sq[2] = fmaf(a2, a2, sq[2]);
            sx[3] += a3; sq[3] = fmaf(a3, a3, sq[3]);
        }
    }
    // block reduce stats: cols c = 4g + j, valid on half==0 lanes
    if (half == 0) {
        red[wid][g][0] = sx[0]; red[wid][g][1] = sx[1];
        red[wid][g][2] = sx[2]; red[wid][g][3] = sx[3];
    }
    __syncthreads();
    if (t < 128) {
        float v = 0.f;
        for (int w = 0; w < 8; ++w) v += red[w][t >> 2][t & 3];
        atomAddF(&accum[t], v);
    }
    __syncthreads();
    if (half == 0) {
        red[wid][g][0] = sq[0]; red[wid][g][1] = sq[1];
        red[wid][g][2] = sq[2]; red[wid][g][3] = sq[3];
    }
    __syncthreads();
    if (t < 128) {
        float v = 0.f;
        for (int w = 0; w < 8; ++w) v += red[w][t >> 2][t & 3];
        atomAddF(&accum[128 + t], v);
    }
}

__global__ void k_bnfinal(float* __restrict__ accum, const float* __restrict__ gamma,
        const float* __restrict__ beta, float inv_n) {
    int c = threadIdx.x;
    float mean = accum[c] * inv_n;
    float var = accum[D_HID + c] * inv_n - mean * mean;
    float sc = gamma[c] * rsqrtf(var + BN_EPS);
    accum[c] = sc;
    accum[D_HID + c] = beta[c] - mean * sc;
}

// l_ext = [ bf16(l) | bf16(l*s) ] (128 cols), l = lrelu(bn(agg)) @ Wmu + bmu,
// s = 1.8/max(||l||,1e-12)
__global__ __launch_bounds__(256) void k_gemm2_mfma(const ushort* __restrict__ agg_bf,
        const float* __restrict__ Wmu, const float* __restrict__ bmu,
        const float* __restrict__ accum, ushort* __restrict__ l_ext, int n, int nwt) {
    __shared__ ushort wf[2][4][4][64][8];  // 32KB
    __shared__ float scs[D_HID], shs[D_HID];
    int t = threadIdx.x;
    for (int i = t; i < 8192; i += 256) {
        int k = i >> 6, nn = i & 63;
        float v = Wmu[i];
        ushort hi = f2bf(v);
        ushort lo = f2bf(v - bf2f(hi));
        int kt = k >> 5, ct = nn >> 4;
        int lane = ((k >> 3) & 3) * 16 + (nn & 15);
        int j = k & 7;
        wf[0][kt][ct][lane][j] = hi;
        wf[1][kt][ct][lane][j] = lo;
    }
    for (int i = t; i < D_HID; i += 256) {
        scs[i] = accum[i];
        shs[i] = accum[D_HID + i];
    }
    __syncthreads();
    int wid = t >> 6, lane = t & 63;
    int lrow = lane & 15, lkg = lane >> 4;
    float bias[4];
#pragma unroll
    for (int ct = 0; ct < 4; ++ct) bias[ct] = bmu[ct * 16 + lrow];
    int stride = gridDim.x * 4;
    for (int wt = blockIdx.x * 4 + wid; wt < nwt; wt += stride) {
        size_t r0 = (size_t)wt * 16;
        int rr = (int)r0 + lrow;
        if (rr >= n) rr = n - 1;
        short8 ah[4], al[4];
#pragma unroll
        for (int kt = 0; kt < 4; ++kt) {
            const ushort* p = agg_bf + (size_t)rr * 128 + kt * 32 + lkg * 8;
            short8 raw = *(const short8*)p;
#pragma unroll
            for (int j = 0; j < 8; ++j) {
                int k = kt * 32 + lkg * 8 + j;
                float v = bf2f((ushort)raw[j]) * scs[k] + shs[k];
                v = v > 0.f ? v : SLOPE * v;
                ushort hb = f2bf(v);
                ah[kt][j] = (short)hb;
                al[kt][j] = (short)f2bf(v - bf2f(hb));
            }
        }
        f32x4 acc[4];
#pragma unroll
        for (int ct = 0; ct < 4; ++ct) {
            float bb = bias[ct];
            acc[ct][0] = bb; acc[ct][1] = bb; acc[ct][2] = bb; acc[ct][3] = bb;
        }
#pragma unroll
        for (int kt = 0; kt < 4; ++kt) {
#pragma unroll
            for (int ct = 0; ct < 4; ++ct) {
                short8 wh = *(const short8*)&wf[0][kt][ct][lane][0];
                short8 wl = *(const short8*)&wf[1][kt][ct][lane][0];
                acc[ct] = __builtin_amdgcn_mfma_f32_16x16x32_bf16(ah[kt], wh, acc[ct], 0, 0, 0);
                acc[ct] = __builtin_amdgcn_mfma_f32_16x16x32_bf16(al[kt], wh, acc[ct], 0, 0, 0);
                acc[ct] = __builtin_amdgcn_mfma_f32_16x16x32_bf16(ah[kt], wl, acc[ct], 0, 0, 0);
            }
        }
#pragma unroll
        for (int j = 0; j < 4; ++j) {
            float ss = acc[0][j] * acc[0][j];
#pragma unroll
            for (int ct = 1; ct < 4; ++ct) ss = fmaf(acc[ct][j], acc[ct][j], ss);
            ss += __shfl_xor(ss, 1, 64);
            ss += __shfl_xor(ss, 2, 64);
            ss += __shfl_xor(ss, 4, 64);
            ss += __shfl_xor(ss, 8, 64);
            float srow = NSCALE / fmaxf(sqrtf(ss), 1e-12f);
            int row = (int)r0 + lkg * 4 + j;
            if (row < n) {
#pragma unroll
                for (int ct = 0; ct < 4; ++ct) {
                    float lv = acc[ct][j];
                    l_ext[(size_t)row * 128 + ct * 16 + lrow] = f2bf(lv);
                    l_ext[(size_t)row * 128 + 64 + ct * 16 + lrow] = f2bf(lv * srow);
                }
            }
        }
    }
}

// pull SpMM2 over l_ext (256B rows: [l | l*s]), split-wave 2 edges/wave, fused reparam.
// half-0 lanes g<16 end up with mu cols [4g..4g+3]; g in 16..31 with logstd cols.
__global__ __launch_bounds__(256) void k_spmm2_csr(const int* __restrict__ rowptr,
        const int2* __restrict__ cw, const uint2* __restrict__ le2,
        const float* __restrict__ dinv, const float* __restrict__ noise,
        float* __restrict__ mu, float* __restrict__ lsd, float* __restrict__ zeta,
        int n) {
    int node = (blockIdx.x << 2) + (threadIdx.x >> 6);
    if (node >= n) return;
    int lane = threadIdx.x & 63;
    int half = lane >> 5, g = lane & 31;
    int beg = rowptr[node], end = rowptr[node + 1];
    float a0 = 0.f, a1 = 0.f, a2 = 0.f, a3 = 0.f;
    if (half == 0) {  // self-loop
        float di = dinv[node];
        float slw = di * di;
        uint2 sv = le2[(size_t)node * 32 + g];
        a0 = bf2f((ushort)(sv.x & 0xffff)) * slw;
        a1 = bf2f((ushort)(sv.x >> 16)) * slw;
        a2 = bf2f((ushort)(sv.y & 0xffff)) * slw;
        a3 = bf2f((ushort)(sv.y >> 16)) * slw;
    }
    int p = beg;
    for (; p + 8 <= end; p += 8) {
        int2 e0 = cw[p + half], e1 = cw[p + 2 + half];
        int2 e2 = cw[p + 4 + half], e3 = cw[p + 6 + half];
        uint2 v0 = le2[(size_t)e0.x * 32 + g];
        uint2 v1 = le2[(size_t)e1.x * 32 + g];
        uint2 v2 = le2[(size_t)e2.x * 32 + g];
        uint2 v3 = le2[(size_t)e3.x * 32 + g];
        float w0 = __int_as_float(e0.y), w1 = __int_as_float(e1.y);
        float w2 = __int_as_float(e2.y), w3 = __int_as_float(e3.y);
        a0 = fmaf(bf2f((ushort)(v0.x & 0xffff)), w0, a0);
        a1 = fmaf(bf2f((ushort)(v0.x >> 16)), w0, a1);
        a2 = fmaf(bf2f((ushort)(v0.y & 0xffff)), w0, a2);
        a3 = fmaf(bf2f((ushort)(v0.y >> 16)), w0, a3);
        a0 = fmaf(bf2f((ushort)(v1.x & 0xffff)), w1, a0);
        a1 = fmaf(bf2f((ushort)(v1.x >> 16)), w1, a1);
        a2 = fmaf(bf2f((ushort)(v1.y & 0xffff)), w1, a2);
        a3 = fmaf(bf2f((ushort)(v1.y >> 16)), w1, a3);
        a0 = fmaf(bf2f((ushort)(v2.x & 0xffff)), w2, a0);
        a1 = fmaf(bf2f((ushort)(v2.x >> 16)), w2, a1);
        a2 = fmaf(bf2f((ushort)(v2.y & 0xffff)), w2, a2);
        a3 = fmaf(bf2f((ushort)(v2.y >> 16)), w2, a3);
        a0 = fmaf(bf2f((ushort)(v3.x & 0xffff)), w3, a0);
        a1 = fmaf(bf2f((ushort)(v3.x >> 16)), w3, a1);
        a2 = fmaf(bf2f((ushort)(v3.y & 0xffff)), w3, a2);
        a3 = fmaf(bf2f((ushort)(v3.y >> 16)), w3, a3);
    }
    for (; p < end; p += 2) {
        int idx = p + half;
        int2 e = cw[(idx < end) ? idx : (end - 1)];
        float w = (idx < end) ? __int_as_float(e.y) : 0.f;
        uint2 v = le2[(size_t)e.x * 32 + g];
        a0 = fmaf(bf2f((ushort)(v.x & 0xffff)), w, a0);
        a1 = fmaf(bf2f((ushort)(v.x >> 16)), w, a1);
        a2 = fmaf(bf2f((ushort)(v.y & 0xffff)), w, a2);
        a3 = fmaf(bf2f((ushort)(v.y >> 16)), w, a3);
    }
    a0 += __shfl_xor(a0, 32, 64);
    a1 += __shfl_xor(a1, 32, 64);
    a2 += __shfl_xor(a2, 32, 64);
    a3 += __shfl_xor(a3, 32, 64);
    // lane g<16 holds mu cols [4g..4g+3]; lane 16<=g<32 holds logstd cols [4(g-16)..]
    float b0 = __shfl_xor(a0, 16, 64);
    float b1 = __shfl_xor(a1, 16, 64);
    float b2 = __shfl_xor(a2, 16, 64);
    float b3 = __shfl_xor(a3, 16, 64);
    if (half == 0) {
        if (g < 16) {
            size_t idx = (size_t)node * 64 + g * 4;
            f32x4 m = {a0, a1, a2, a3};
            *(f32x4*)(mu + idx) = m;
            f32x4 nz = *(const f32x4*)(noise + idx);
            f32x4 z;
            z[0] = a0 + nz[0] * expf(b0);
            z[1] = a1 + nz[1] * expf(b1);
            z[2] = a2 + nz[2] * expf(b2);
            z[3] = a3 + nz[3] * expf(b3);
            *(f32x4*)(zeta + idx) = z;
        } else {
            size_t idx = (size_t)node * 64 + (g - 16) * 4;
            f32x4 ls = {a0, a1, a2, a3};
            *(f32x4*)(lsd + idx) = ls;
        }
    }
}

extern "C" void kernel_launch(void* const* d_in, const int* in_sizes, int n_in,
                              void* d_out, int out_size, void* d_ws, size_t ws_size,
                              hipStream_t stream) {
    const float* x     = (const float*)d_in[0];
    const int*   esrc  = (const int*)d_in[1];
    const int*   edst  = (const int*)d_in[2];
    const float* W1    = (const float*)d_in[3];
    const float* b1    = (const float*)d_in[4];
    const float* gamma = (const float*)d_in[5];
    const float* beta  = (const float*)d_in[6];
    const float* Wmu   = (const float*)d_in[7];
    const float* bmu   = (const float*)d_in[8];
    const float* noise = (const float*)d_in[9];
    int N = in_sizes[0] / D_IN;
    int E = in_sizes[1];
    int nb = (N + 255) / 256;
    int nwt = (N + 15) / 16;

    float* out  = (float*)d_out;
    float* mu   = out;
    float* lsd  = out + (size_t)N * D_OUT;
    float* zeta = out + 2 * (size_t)N * D_OUT;

    char* ws = (char*)d_ws;
    size_t off = 0;
    auto alloc = [&](size_t bytes) {
        void* p = ws + off;
        off += (bytes + 255) & ~(size_t)255;
        return p;
    };
    int* deg      = (int*)alloc((size_t)N * 4);
    int* cursor   = (int*)alloc((size_t)N * 4);
    float* accum  = (float*)alloc(1024);
    size_t zbytes = off;  // deg + cursor + accum zeroed
    float* dinv   = (float*)alloc((size_t)N * 4);
    int* rowptr   = (int*)alloc(((size_t)N + 1) * 4);
    int* bsum     = (int*)alloc(2048);
    int2* cw      = (int2*)alloc((size_t)E * 8);
    ushort* h_bf  = (ushort*)alloc((size_t)N * D_HID * 2);
    uint2* agg_bf = (uint2*)alloc((size_t)N * D_HID * 2);
    ushort* l_ext = (ushort*)alloc((size_t)N * 128 * 2);

    hipMemsetAsync(d_ws, 0, zbytes, stream);

    k_deg<<<(E + 255) / 256, 256, 0, stream>>>(edst, deg, E);
    k_scanA<<<nb, 256, 0, stream>>>(deg, bsum, N);
    k_scanB<<<1, 512, 0, stream>>>(bsum, nb);
    k_scanC<<<nb, 256, 0, stream>>>(deg, bsum, rowptr, dinv, N);
    k_scatter<<<(E + 255) / 256, 256, 0, stream>>>(esrc, edst, rowptr, cursor, dinv, cw, E);
    k_gemm1_mfma<<<512, 256, 0, stream>>>(x, W1, b1, h_bf, N, nwt);
    k_spmm1_csr<<<1024, 512, 0, stream>>>(rowptr, cw, (const uint2*)h_bf, dinv, agg_bf, accum, N);
    k_bnfinal<<<1, 128, 0, stream>>>(accum, gamma, beta, 1.0f / (float)N);
    k_gemm2_mfma<<<512, 256, 0, stream>>>((const ushort*)agg_bf, Wmu, bmu, accum, l_ext, N, nwt);
    k_spmm2_csr<<<(N + 3) / 4, 256, 0, stream>>>(rowptr, cw, (const uint2*)l_ext, dinv, noise, mu, lsd, zeta, N);
}

// Round 6
// 408.136 us; speedup vs baseline: 5.9528x; 1.0115x over previous
//
#include <hip/hip_runtime.h>
#include <hip/hip_bf16.h>
#include <math.h>

#define D_IN 128
#define D_HID 128
#define D_OUT 64
#define BN_EPS 1e-5f
#define SLOPE 0.01f
#define NSCALE 1.8f

typedef __attribute__((ext_vector_type(8))) short short8;
typedef __attribute__((ext_vector_type(4))) float f32x4;

__device__ inline void atomAddF(float* p, float v) {
#if defined(__gfx90a__) || defined(__gfx942__) || defined(__gfx950__)
    unsafeAtomicAdd(p, v);
#else
    atomicAdd(p, v);
#endif
}

__device__ inline ushort f2bf(float f) {  // RNE
    union { float f; uint u; } v; v.f = f;
    uint r = v.u + 0x7fff + ((v.u >> 16) & 1);
    return (ushort)(r >> 16);
}
__device__ inline float bf2f(ushort b) {
    union { uint u; float f; } v; v.u = ((uint)b) << 16;
    return v.f;
}
__device__ inline float bflo(uint u) { return __uint_as_float(u << 16); }
__device__ inline float bfhi(uint u) { return __uint_as_float(u & 0xffff0000u); }

// a[j] += row-col (8g+j) * w, row delivered as uint4 (8 bf16, memory order)
__device__ inline void fma8(uint4 v, float w, float a[8]) {
    a[0] = fmaf(bflo(v.x), w, a[0]);
    a[1] = fmaf(bfhi(v.x), w, a[1]);
    a[2] = fmaf(bflo(v.y), w, a[2]);
    a[3] = fmaf(bfhi(v.y), w, a[3]);
    a[4] = fmaf(bflo(v.z), w, a[4]);
    a[5] = fmaf(bfhi(v.z), w, a[5]);
    a[6] = fmaf(bflo(v.w), w, a[6]);
    a[7] = fmaf(bfhi(v.w), w, a[7]);
}

__global__ void k_deg(const int* __restrict__ dst, int* __restrict__ deg, int E) {
    int e = blockIdx.x * blockDim.x + threadIdx.x;
    if (e < E) atomicAdd(&deg[dst[e]], 1);
}

// --- scan: rowptr = exclusive_prefix(deg); also dinv = rsqrt(deg+1) -----
__global__ void k_scanA(const int* __restrict__ deg, int* __restrict__ bsum, int n) {
    __shared__ int sh[256];
    int i = blockIdx.x * 256 + threadIdx.x;
    sh[threadIdx.x] = (i < n) ? deg[i] : 0;
    __syncthreads();
    for (int off = 128; off >= 1; off >>= 1) {
        if (threadIdx.x < off) sh[threadIdx.x] += sh[threadIdx.x + off];
        __syncthreads();
    }
    if (threadIdx.x == 0) bsum[blockIdx.x] = sh[0];
}

__global__ void k_scanB(int* __restrict__ bsum, int nb) {  // single block, nb <= 512
    __shared__ int sh[512];
    int v = (threadIdx.x < nb) ? bsum[threadIdx.x] : 0;
    sh[threadIdx.x] = v;
    __syncthreads();
    for (int off = 1; off < 512; off <<= 1) {
        int t = (threadIdx.x >= off) ? sh[threadIdx.x - off] : 0;
        __syncthreads();
        sh[threadIdx.x] += t;
        __syncthreads();
    }
    if (threadIdx.x < nb) bsum[threadIdx.x] = sh[threadIdx.x] - v;  // exclusive
}

__global__ void k_scanC(const int* __restrict__ deg, const int* __restrict__ bsum,
                        int* __restrict__ rowptr, float* __restrict__ dinv, int n) {
    __shared__ int sh[256];
    int i = blockIdx.x * 256 + threadIdx.x;
    int v = (i < n) ? deg[i] : 0;
    sh[threadIdx.x] = v;
    __syncthreads();
    for (int off = 1; off < 256; off <<= 1) {
        int t = (threadIdx.x >= off) ? sh[threadIdx.x - off] : 0;
        __syncthreads();
        sh[threadIdx.x] += t;
        __syncthreads();
    }
    int excl = sh[threadIdx.x] - v + bsum[blockIdx.x];
    if (i < n) {
        rowptr[i] = excl;
        dinv[i] = rsqrtf((float)v + 1.0f);
    }
    if (i == n - 1) rowptr[n] = excl + v;
}

// scatter edges into CSR (by dst), packed (col, wgt) as int2 -> one 8B store
__global__ void k_scatter(const int* __restrict__ src, const int* __restrict__ dst,
                          const int* __restrict__ rowptr, int* __restrict__ cursor,
                          const float* __restrict__ dinv, int2* __restrict__ cw, int E) {
    int e = blockIdx.x * blockDim.x + threadIdx.x;
    if (e >= E) return;
    int d = dst[e], s = src[e];
    int p = rowptr[d] + atomicAdd(&cursor[d], 1);
    int2 v;
    v.x = s;
    v.y = __float_as_int(dinv[s] * dinv[d]);
    cw[p] = v;
}

// h_bf = bf16(x @ W1 + b1). Split-bf16 MFMA (hi/lo), W1 fragments staged in LDS.
__global__ __launch_bounds__(256) void k_gemm1_mfma(const float* __restrict__ x,
        const float* __restrict__ W1, const float* __restrict__ b1,
        ushort* __restrict__ h_bf, int n, int nwt) {
    __shared__ ushort wf[2][4][8][64][8];  // [hi/lo][kt][ct][lane][j] = 64KB
    int t = threadIdx.x;
    for (int i = t; i < 16384; i += 256) {
        int k = i >> 7, nn = i & 127;
        float v = W1[i];
        ushort hi = f2bf(v);
        ushort lo = f2bf(v - bf2f(hi));
        int kt = k >> 5, ct = nn >> 4;
        int lane = ((k >> 3) & 3) * 16 + (nn & 15);
        int j = k & 7;
        wf[0][kt][ct][lane][j] = hi;
        wf[1][kt][ct][lane][j] = lo;
    }
    __syncthreads();
    int wid = t >> 6, lane = t & 63;
    int lrow = lane & 15, lkg = lane >> 4;
    float bias[8];
#pragma unroll
    for (int ct = 0; ct < 8; ++ct) bias[ct] = b1[ct * 16 + lrow];
    int stride = gridDim.x * 4;
    for (int wt = blockIdx.x * 4 + wid; wt < nwt; wt += stride) {
        size_t r0 = (size_t)wt * 16;
        int rr = (int)r0 + lrow;
        if (rr >= n) rr = n - 1;
        short8 ah[4], al[4];
#pragma unroll
        for (int kt = 0; kt < 4; ++kt) {
            const float* p = x + (size_t)rr * 128 + kt * 32 + lkg * 8;
            float va[8];
            *(f32x4*)&va[0] = *(const f32x4*)p;
            *(f32x4*)&va[4] = *(const f32x4*)(p + 4);
#pragma unroll
            for (int j = 0; j < 8; ++j) {
                ushort hb = f2bf(va[j]);
                ah[kt][j] = (short)hb;
                al[kt][j] = (short)f2bf(va[j] - bf2f(hb));
            }
        }
        f32x4 acc[8];
#pragma unroll
        for (int ct = 0; ct < 8; ++ct) {
            float bb = bias[ct];
            acc[ct][0] = bb; acc[ct][1] = bb; acc[ct][2] = bb; acc[ct][3] = bb;
        }
#pragma unroll
        for (int kt = 0; kt < 4; ++kt) {
#pragma unroll
            for (int ct = 0; ct < 8; ++ct) {
                short8 wh = *(const short8*)&wf[0][kt][ct][lane][0];
                short8 wl = *(const short8*)&wf[1][kt][ct][lane][0];
                acc[ct] = __builtin_amdgcn_mfma_f32_16x16x32_bf16(ah[kt], wh, acc[ct], 0, 0, 0);
                acc[ct] = __builtin_amdgcn_mfma_f32_16x16x32_bf16(al[kt], wh, acc[ct], 0, 0, 0);
                acc[ct] = __builtin_amdgcn_mfma_f32_16x16x32_bf16(ah[kt], wl, acc[ct], 0, 0, 0);
            }
        }
#pragma unroll
        for (int j = 0; j < 4; ++j) {
            int row = (int)r0 + lkg * 4 + j;
            if (row < n) {
#pragma unroll
                for (int ct = 0; ct < 8; ++ct)
                    h_bf[(size_t)row * 128 + ct * 16 + lrow] = f2bf(acc[ct][j]);
            }
        }
    }
}

// pull SpMM1, quarter-wave: 4 edges/wave concurrent (16 lanes x uint4 = 256B row),
// main loop holds 16 edges in flight. Fused BN partial stats. agg packed bf16.
__global__ __launch_bounds__(512) void k_spmm1_csr(const int* __restrict__ rowptr,
        const int2* __restrict__ cw, const uint4* __restrict__ hb4,
        const float* __restrict__ dinv, uint4* __restrict__ agg_bf,
        float* __restrict__ accum, int n) {
    __shared__ float red[8][16][8];
    int t = threadIdx.x;
    int wid = t >> 6, lane = t & 63;
    int q = lane >> 4, g = lane & 15;
    int gw = blockIdx.x * 8 + wid;
    int nw = gridDim.x * 8;
    float sx[8], sq[8];
#pragma unroll
    for (int j = 0; j < 8; ++j) { sx[j] = 0.f; sq[j] = 0.f; }
    for (int node = gw; node < n; node += nw) {
        int beg = rowptr[node], end = rowptr[node + 1];
        float a[8];
#pragma unroll
        for (int j = 0; j < 8; ++j) a[j] = 0.f;
        if (q == 0) {  // self-loop on quarter 0
            float di = dinv[node];
            uint4 sv = hb4[(size_t)node * 16 + g];
            fma8(sv, di * di, a);
        }
        int p = beg;
        for (; p + 16 <= end; p += 16) {
            int2 e0 = cw[p + q], e1 = cw[p + 4 + q];
            int2 e2 = cw[p + 8 + q], e3 = cw[p + 12 + q];
            uint4 v0 = hb4[(size_t)e0.x * 16 + g];
            uint4 v1 = hb4[(size_t)e1.x * 16 + g];
            uint4 v2 = hb4[(size_t)e2.x * 16 + g];
            uint4 v3 = hb4[(size_t)e3.x * 16 + g];
            fma8(v0, __int_as_float(e0.y), a);
            fma8(v1, __int_as_float(e1.y), a);
            fma8(v2, __int_as_float(e2.y), a);
            fma8(v3, __int_as_float(e3.y), a);
        }
        if (p + 8 <= end) {
            int2 e0 = cw[p + q], e1 = cw[p + 4 + q];
            uint4 v0 = hb4[(size_t)e0.x * 16 + g];
            uint4 v1 = hb4[(size_t)e1.x * 16 + g];
            fma8(v0, __int_as_float(e0.y), a);
            fma8(v1, __int_as_float(e1.y), a);
            p += 8;
        }
        if (p < end) {
            int i0 = p + q, i1 = p + 4 + q;
            int2 e0 = cw[i0 < end ? i0 : end - 1];
            int2 e1 = cw[i1 < end ? i1 : end - 1];
            float w0 = (i0 < end) ? __int_as_float(e0.y) : 0.f;
            float w1 = (i1 < end) ? __int_as_float(e1.y) : 0.f;
            uint4 v0 = hb4[(size_t)e0.x * 16 + g];
            uint4 v1 = hb4[(size_t)e1.x * 16 + g];
            fma8(v0, w0, a);
            fma8(v1, w1, a);
        }
        // combine quarters
#pragma unroll
        for (int j = 0; j < 8; ++j) {
            a[j] += __shfl_xor(a[j], 16, 64);
            a[j] += __shfl_xor(a[j], 32, 64);
        }
        if (q == 0) {
            uint4 pk;
            pk.x = ((uint)f2bf(a[1]) << 16) | (uint)f2bf(a[0]);
            pk.y = ((uint)f2bf(a[3]) << 16) | (uint)f2bf(a[2]);
            pk.z = ((uint)f2bf(a[5]) << 16) | (uint)f2bf(a[4]);
            pk.w = ((uint)f2bf(a[7]) << 16) | (uint)f2bf(a[6]);
            agg_bf[(size_t)node * 16 + g] = pk;
#pragma unroll
            for (int j = 0; j < 8; ++j) {
                sx[j] += a[j];
                sq[j] = fmaf(a[j], a[j], sq[j]);
            }
        }
    }
    // block reduce stats: col = 8g + j = t for t < 128
    if (q == 0) {
#pragma unroll
        for (int j = 0; j < 8; ++j) red[wid][g][j] = sx[j];
    }
    __syncthreads();
    if (t < 128) {
        float v = 0.f;
        for (int w = 0; w < 8; ++w) v += red[w][t >> 3][t & 7];
        atomAddF(&accum[t], v);
    }
    __syncthreads();
    if (q == 0) {
#pragma unroll
        for (int j = 0; j < 8; ++j) red[wid][g][j] = sq[j];
    }
    __syncthreads();
    if (t < 128) {
        float v = 0.f;
        for (int w = 0; w < 8; ++w) v += red[w][t >> 3][t & 7];
        atomAddF(&accum[128 + t], v);
    }
}

__global__ void k_bnfinal(float* __restrict__ accum, const float* __restrict__ gamma,
        const float* __restrict__ beta, float inv_n) {
    int c = threadIdx.x;
    float mean = accum[c] * inv_n;
    float var = accum[D_HID + c] * inv_n - mean * mean;
    float sc = gamma[c] * rsqrtf(var + BN_EPS);
    accum[c] = sc;
    accum[D_HID + c] = beta[c] - mean * sc;
}

// l_ext = [ bf16(l) | bf16(l*s) ] (128 cols), l = lrelu(bn(agg)) @ Wmu + bmu,
// s = 1.8/max(||l||,1e-12)
__global__ __launch_bounds__(256) void k_gemm2_mfma(const ushort* __restrict__ agg_bf,
        const float* __restrict__ Wmu, const float* __restrict__ bmu,
        const float* __restrict__ accum, ushort* __restrict__ l_ext, int n, int nwt) {
    __shared__ ushort wf[2][4][4][64][8];  // 32KB
    __shared__ float scs[D_HID], shs[D_HID];
    int t = threadIdx.x;
    for (int i = t; i < 8192; i += 256) {
        int k = i >> 6, nn = i & 63;
        float v = Wmu[i];
        ushort hi = f2bf(v);
        ushort lo = f2bf(v - bf2f(hi));
        int kt = k >> 5, ct = nn >> 4;
        int lane = ((k >> 3) & 3) * 16 + (nn & 15);
        int j = k & 7;
        wf[0][kt][ct][lane][j] = hi;
        wf[1][kt][ct][lane][j] = lo;
    }
    for (int i = t; i < D_HID; i += 256) {
        scs[i] = accum[i];
        shs[i] = accum[D_HID + i];
    }
    __syncthreads();
    int wid = t >> 6, lane = t & 63;
    int lrow = lane & 15, lkg = lane >> 4;
    float bias[4];
#pragma unroll
    for (int ct = 0; ct < 4; ++ct) bias[ct] = bmu[ct * 16 + lrow];
    int stride = gridDim.x * 4;
    for (int wt = blockIdx.x * 4 + wid; wt < nwt; wt += stride) {
        size_t r0 = (size_t)wt * 16;
        int rr = (int)r0 + lrow;
        if (rr >= n) rr = n - 1;
        short8 ah[4], al[4];
#pragma unroll
        for (int kt = 0; kt < 4; ++kt) {
            const ushort* p = agg_bf + (size_t)rr * 128 + kt * 32 + lkg * 8;
            short8 raw = *(const short8*)p;
#pragma unroll
            for (int j = 0; j < 8; ++j) {
                int k = kt * 32 + lkg * 8 + j;
                float v = bf2f((ushort)raw[j]) * scs[k] + shs[k];
                v = v > 0.f ? v : SLOPE * v;
                ushort hb = f2bf(v);
                ah[kt][j] = (short)hb;
                al[kt][j] = (short)f2bf(v - bf2f(hb));
            }
        }
        f32x4 acc[4];
#pragma unroll
        for (int ct = 0; ct < 4; ++ct) {
            float bb = bias[ct];
            acc[ct][0] = bb; acc[ct][1] = bb; acc[ct][2] = bb; acc[ct][3] = bb;
        }
#pragma unroll
        for (int kt = 0; kt < 4; ++kt) {
#pragma unroll
            for (int ct = 0; ct < 4; ++ct) {
                short8 wh = *(const short8*)&wf[0][kt][ct][lane][0];
                short8 wl = *(const short8*)&wf[1][kt][ct][lane][0];
                acc[ct] = __builtin_amdgcn_mfma_f32_16x16x32_bf16(ah[kt], wh, acc[ct], 0, 0, 0);
                acc[ct] = __builtin_amdgcn_mfma_f32_16x16x32_bf16(al[kt], wh, acc[ct], 0, 0, 0);
                acc[ct] = __builtin_amdgcn_mfma_f32_16x16x32_bf16(ah[kt], wl, acc[ct], 0, 0, 0);
            }
        }
#pragma unroll
        for (int j = 0; j < 4; ++j) {
            float ss = acc[0][j] * acc[0][j];
#pragma unroll
            for (int ct = 1; ct < 4; ++ct) ss = fmaf(acc[ct][j], acc[ct][j], ss);
            ss += __shfl_xor(ss, 1, 64);
            ss += __shfl_xor(ss, 2, 64);
            ss += __shfl_xor(ss, 4, 64);
            ss += __shfl_xor(ss, 8, 64);
            float srow = NSCALE / fmaxf(sqrtf(ss), 1e-12f);
            int row = (int)r0 + lkg * 4 + j;
            if (row < n) {
#pragma unroll
                for (int ct = 0; ct < 4; ++ct) {
                    float lv = acc[ct][j];
                    l_ext[(size_t)row * 128 + ct * 16 + lrow] = f2bf(lv);
                    l_ext[(size_t)row * 128 + 64 + ct * 16 + lrow] = f2bf(lv * srow);
                }
            }
        }
    }
}

// pull SpMM2 over l_ext (256B rows: [l | l*s]), quarter-wave, fused reparam.
// After quarter-combine, lane g<8 holds mu cols [8g..8g+7]; g>=8 logstd cols.
__global__ __launch_bounds__(512) void k_spmm2_csr(const int* __restrict__ rowptr,
        const int2* __restrict__ cw, const uint4* __restrict__ le4,
        const float* __restrict__ dinv, const float* __restrict__ noise,
        float* __restrict__ mu, float* __restrict__ lsd, float* __restrict__ zeta,
        int n) {
    int node = blockIdx.x * 8 + ((int)threadIdx.x >> 6);
    if (node >= n) return;
    int lane = threadIdx.x & 63;
    int q = lane >> 4, g = lane & 15;
    int beg = rowptr[node], end = rowptr[node + 1];
    float a[8];
#pragma unroll
    for (int j = 0; j < 8; ++j) a[j] = 0.f;
    if (q == 0) {  // self-loop
        float di = dinv[node];
        uint4 sv = le4[(size_t)node * 16 + g];
        fma8(sv, di * di, a);
    }
    int p = beg;
    for (; p + 16 <= end; p += 16) {
        int2 e0 = cw[p + q], e1 = cw[p + 4 + q];
        int2 e2 = cw[p + 8 + q], e3 = cw[p + 12 + q];
        uint4 v0 = le4[(size_t)e0.x * 16 + g];
        uint4 v1 = le4[(size_t)e1.x * 16 + g];
        uint4 v2 = le4[(size_t)e2.x * 16 + g];
        uint4 v3 = le4[(size_t)e3.x * 16 + g];
        fma8(v0, __int_as_float(e0.y), a);
        fma8(v1, __int_as_float(e1.y), a);
        fma8(v2, __int_as_float(e2.y), a);
        fma8(v3, __int_as_float(e3.y), a);
    }
    if (p + 8 <= end) {
        int2 e0 = cw[p + q], e1 = cw[p + 4 + q];
        uint4 v0 = le4[(size_t)e0.x * 16 + g];
        uint4 v1 = le4[(size_t)e1.x * 16 + g];
        fma8(v0, __int_as_float(e0.y), a);
        fma8(v1, __int_as_float(e1.y), a);
        p += 8;
    }
    if (p < end) {
        int i0 = p + q, i1 = p + 4 + q;
        int2 e0 = cw[i0 < end ? i0 : end - 1];
        int2 e1 = cw[i1 < end ? i1 : end - 1];
        float w0 = (i0 < end) ? __int_as_float(e0.y) : 0.f;
        float w1 = (i1 < end) ? __int_as_float(e1.y) : 0.f;
        uint4 v0 = le4[(size_t)e0.x * 16 + g];
        uint4 v1 = le4[(size_t)e1.x * 16 + g];
        fma8(v0, w0, a);
        fma8(v1, w1, a);
    }
#pragma unroll
    for (int j = 0; j < 8; ++j) {
        a[j] += __shfl_xor(a[j], 16, 64);
        a[j] += __shfl_xor(a[j], 32, 64);
    }
    // pair mu lane (g<8) with logstd lane (g+8)
    float b[8];
#pragma unroll
    for (int j = 0; j < 8; ++j) b[j] = __shfl_xor(a[j], 8, 64);
    if (q == 0) {
        if (g < 8) {
            size_t idx = (size_t)node * 64 + g * 8;
            f32x4 m0 = {a[0], a[1], a[2], a[3]};
            f32x4 m1 = {a[4], a[5], a[6], a[7]};
            *(f32x4*)(mu + idx) = m0;
            *(f32x4*)(mu + idx + 4) = m1;
            f32x4 n0 = *(const f32x4*)(noise + idx);
            f32x4 n1 = *(const f32x4*)(noise + idx + 4);
            f32x4 z0, z1;
            z0[0] = a[0] + n0[0] * expf(b[0]);
            z0[1] = a[1] + n0[1] * expf(b[1]);
            z0[2] = a[2] + n0[2] * expf(b[2]);
            z0[3] = a[3] + n0[3] * expf(b[3]);
            z1[0] = a[4] + n1[0] * expf(b[4]);
            z1[1] = a[5] + n1[1] * expf(b[5]);
            z1[2] = a[6] + n1[2] * expf(b[6]);
            z1[3] = a[7] + n1[3] * expf(b[7]);
            *(f32x4*)(zeta + idx) = z0;
            *(f32x4*)(zeta + idx + 4) = z1;
        } else {
            size_t idx = (size_t)node * 64 + (g - 8) * 8;
            f32x4 l0 = {a[0], a[1], a[2], a[3]};
            f32x4 l1 = {a[4], a[5], a[6], a[7]};
            *(f32x4*)(lsd + idx) = l0;
            *(f32x4*)(lsd + idx + 4) = l1;
        }
    }
}

extern "C" void kernel_launch(void* const* d_in, const int* in_sizes, int n_in,
                              void* d_out, int out_size, void* d_ws, size_t ws_size,
                              hipStream_t stream) {
    const float* x     = (const float*)d_in[0];
    const int*   esrc  = (const int*)d_in[1];
    const int*   edst  = (const int*)d_in[2];
    const float* W1    = (const float*)d_in[3];
    const float* b1    = (const float*)d_in[4];
    const float* gamma = (const float*)d_in[5];
    const float* beta  = (const float*)d_in[6];
    const float* Wmu   = (const float*)d_in[7];
    const float* bmu   = (const float*)d_in[8];
    const float* noise = (const float*)d_in[9];
    int N = in_sizes[0] / D_IN;
    int E = in_sizes[1];
    int nb = (N + 255) / 256;
    int nwt = (N + 15) / 16;

    float* out  = (float*)d_out;
    float* mu   = out;
    float* lsd  = out + (size_t)N * D_OUT;
    float* zeta = out + 2 * (size_t)N * D_OUT;

    char* ws = (char*)d_ws;
    size_t off = 0;
    auto alloc = [&](size_t bytes) {
        void* p = ws + off;
        off += (bytes + 255) & ~(size_t)255;
        return p;
    };
    int* deg      = (int*)alloc((size_t)N * 4);
    int* cursor   = (int*)alloc((size_t)N * 4);
    float* accum  = (float*)alloc(1024);
    size_t zbytes = off;  // deg + cursor + accum zeroed
    float* dinv   = (float*)alloc((size_t)N * 4);
    int* rowptr   = (int*)alloc(((size_t)N + 1) * 4);
    int* bsum     = (int*)alloc(2048);
    int2* cw      = (int2*)alloc((size_t)E * 8);
    ushort* h_bf  = (ushort*)alloc((size_t)N * D_HID * 2);
    uint4* agg_bf = (uint4*)alloc((size_t)N * D_HID * 2);
    ushort* l_ext = (ushort*)alloc((size_t)N * 128 * 2);

    hipMemsetAsync(d_ws, 0, zbytes, stream);

    k_deg<<<(E + 255) / 256, 256, 0, stream>>>(edst, deg, E);
    k_scanA<<<nb, 256, 0, stream>>>(deg, bsum, N);
    k_scanB<<<1, 512, 0, stream>>>(bsum, nb);
    k_scanC<<<nb, 256, 0, stream>>>(deg, bsum, rowptr, dinv, N);
    k_scatter<<<(E + 255) / 256, 256, 0, stream>>>(esrc, edst, rowptr, cursor, dinv, cw, E);
    k_gemm1_mfma<<<512, 256, 0, stream>>>(x, W1, b1, h_bf, N, nwt);
    k_spmm1_csr<<<1024, 512, 0, stream>>>(rowptr, cw, (const uint4*)h_bf, dinv, agg_bf, accum, N);
    k_bnfinal<<<1, 128, 0, stream>>>(accum, gamma, beta, 1.0f / (float)N);
    k_gemm2_mfma<<<512, 256, 0, stream>>>((const ushort*)agg_bf, Wmu, bmu, accum, l_ext, N, nwt);
    k_spmm2_csr<<<(N + 7) / 8, 512, 0, stream>>>(rowptr, cw, (const uint4*)l_ext, dinv, noise, mu, lsd, zeta, N);
}